// Round 4
// baseline (898.711 us; speedup 1.0000x reference)
//
#include <hip/hip_runtime.h>

#define N_NODES 100000
#define N_EDGES 1600000
#define D 64

// ---- aggregation geometry ----
#define NPB   240                          // nodes per bucket (60KB LDS acc)
#define NB    417                          // ceil(100000/240)
#define NIDX  (NB * 8)                     // (bucket, color) regions = 3336
#define PART_BLOCKS (N_EDGES / 256)        // 6250, color = blockIdx & 7

// ---- update geometry: 2500 blocks x 10 passes x 4 nodes = 100000 ----
#define UPD_BLOCKS 2500
#define NPP 4
#define PASSES (N_NODES / (UPD_BLOCKS * NPP))   // 10

// ---- d_ws layout (bytes) ----
#define WS_PACKED   0u                          // int[N_EDGES]      6.40 MB
#define WS_CNT      (4u * N_EDGES)              // int[NIDX]
#define WS_OFF      (WS_CNT + 4u * NIDX)        // int[NIDX]
#define WS_CURPAD   (WS_OFF + 4u * NIDX)        // int[NIDX*16] (64B-strided)
#define WS_NEED     (WS_CURPAD + 64u * NIDX)    // ~6.64 MB
#define WS_DEG      0u                          // fallback: float[N_NODES]

// ===========================================================================
// 1) Histogram: edges per (bucket, color).  color must match what the
//    partition pass will use: partition block b = e>>8, color = b & 7.
// ===========================================================================
__global__ __launch_bounds__(256) void k_hist(
    const int* __restrict__ dst, int* __restrict__ cnt)
{
    __shared__ int h[NIDX];
    const int t = threadIdx.x;
    for (int i = t; i < NIDX; i += 256) h[i] = 0;
    __syncthreads();

    for (int e = blockIdx.x * 256 + t; e < N_EDGES; e += gridDim.x * 256) {
        const int d     = dst[e];
        const int color = (e >> 8) & 7;
        atomicAdd(&h[(d / NPB) * 8 + color], 1);
    }
    __syncthreads();
    for (int i = t; i < NIDX; i += 256)
        if (h[i]) atomicAdd(&cnt[i], h[i]);
}

// ===========================================================================
// 2) Exclusive scan of cnt[NIDX] -> off, and seed the padded cursors.
//    Single block, 1024 threads x 4 values.
// ===========================================================================
__global__ __launch_bounds__(1024) void k_scan(
    const int* __restrict__ cnt, int* __restrict__ off, int* __restrict__ curpad)
{
    __shared__ int lds[1024];
    const int t = threadIdx.x;

    int v[4], s = 0;
    #pragma unroll
    for (int k = 0; k < 4; ++k) {
        const int i = t * 4 + k;
        v[k] = (i < NIDX) ? cnt[i] : 0;
        s += v[k];
    }
    lds[t] = s;
    __syncthreads();
    for (int o = 1; o < 1024; o <<= 1) {
        const int x = (t >= o) ? lds[t - o] : 0;
        __syncthreads();
        lds[t] += x;
        __syncthreads();
    }
    int excl = lds[t] - s;   // exclusive prefix of this thread's 4-group
    #pragma unroll
    for (int k = 0; k < 4; ++k) {
        const int i = t * 4 + k;
        if (i < NIDX) {
            off[i] = excl;
            curpad[i * 16] = excl;
            excl += v[k];
        }
    }
}

// ===========================================================================
// 3) Partition: append packed (src | dstLocal<<17) to region (bucket, b&7).
//    Each color's tails are written by one XCD -> lines fill before writeback.
// ===========================================================================
__global__ __launch_bounds__(256) void k_partition(
    const int* __restrict__ src, const int* __restrict__ dst,
    int* __restrict__ curpad, int* __restrict__ packed)
{
    const int e = blockIdx.x * 256 + threadIdx.x;
    const int color = blockIdx.x & 7;
    const int d = dst[e];
    const int b = d / NPB;
    const int dl = d - b * NPB;
    const int pos = atomicAdd(&curpad[(b * 8 + color) * 16], 1);
    packed[pos] = src[e] | (dl << 17);
}

// ===========================================================================
// 4) Aggregate: one block per bucket; LDS accumulator 240x64 f32.
//    Wave reads 64 packed records coalesced, broadcasts each via shfl,
//    gathers the 256B feat row, LDS-atomic-adds it.  Writes the MEAN to out.
// ===========================================================================
__global__ __launch_bounds__(512, 2) void k_agg(
    const float* __restrict__ feat,
    const int*   __restrict__ off,
    const int*   __restrict__ cnt,
    const int*   __restrict__ packed,
    float*       __restrict__ out)
{
    __shared__ float acc[NPB * D];   // 60 KB
    __shared__ int   degs[NPB];

    const int t      = threadIdx.x;
    const int bucket = blockIdx.x;
    const int w      = t >> 6;       // wave 0..7
    const int lane   = t & 63;

    for (int j = t; j < NPB * D; j += 512) acc[j] = 0.0f;
    for (int j = t; j < NPB; j += 512) degs[j] = 0;
    __syncthreads();

    for (int c = 0; c < 8; ++c) {
        const int idx   = bucket * 8 + c;
        const int start = off[idx];
        const int n     = cnt[idx];
        for (int base = w * 64; base < n; base += 8 * 64) {
            const int k = base + lane;
            const int p = (k < n) ? packed[start + k] : 0;
            const int m = min(64, n - base);
            #pragma unroll 4
            for (int i = 0; i < m; ++i) {
                const int pi = __shfl(p, i);
                const int s  = pi & 0x1FFFF;
                const int dl = pi >> 17;
                atomicAdd(&acc[dl * D + lane], feat[s * D + lane]);
                if (lane == 0) atomicAdd(&degs[dl], 1);
            }
        }
    }
    __syncthreads();

    for (int j = t; j < NPB * D; j += 512) {
        const int nl = j >> 6;
        const int n  = bucket * NPB + nl;
        if (n < N_NODES) {
            const float inv = 1.0f / (float)max(degs[nl], 1);
            out[n * D + (j & 63)] = acc[j] * inv;
        }
    }
}

// ===========================================================================
// 5) Dense update (R2 structure, W in registers).  DIV only on fallback.
// ===========================================================================
template <bool DIV>
__global__ __launch_bounds__(256) void sage_update(
    const float* __restrict__ feat,
    const float* __restrict__ Ws,
    const float* __restrict__ Wn,
    const float* __restrict__ deg,
    float* out)
{
    __shared__ float4 fLDS[2][NPP * 16];
    __shared__ float4 aLDS[2][NPP * 16];

    const int t  = threadIdx.x;
    const int c  = t & 63;
    const int nl = t >> 6;

    const float4* Ws4 = (const float4*)Ws;
    const float4* Wn4 = (const float4*)Wn;
    float4 ws[16], wn[16];
    #pragma unroll
    for (int j = 0; j < 16; ++j) {
        ws[j] = Ws4[c * 16 + j];
        wn[j] = Wn4[c * 16 + j];
    }

    const int node0 = blockIdx.x * (NPP * PASSES);
    const float4* feat4 = (const float4*)feat;
    const float4* out4  = (const float4*)out;

    {
        const int b4 = node0 * 16;
        if (t < 64)        fLDS[0][t]      = feat4[b4 + t];
        else if (t < 128)  aLDS[0][t - 64] = out4[b4 + (t - 64)];
    }
    __syncthreads();

    for (int p = 0; p < PASSES; ++p) {
        const int buf  = p & 1;
        const int base = node0 + p * NPP;

        float4 fnx, anx;
        const bool pref = (p + 1 < PASSES) && (t < 128);
        if (pref) {
            const int b4 = (node0 + (p + 1) * NPP) * 16;
            if (t < 64) fnx = feat4[b4 + t];
            else        anx = out4[b4 + (t - 64)];
        }

        float accs = 0.0f, accn = 0.0f;
        #pragma unroll
        for (int j = 0; j < 16; ++j) {
            const float4 f = fLDS[buf][nl * 16 + j];
            accs = fmaf(f.x, ws[j].x, accs);
            accs = fmaf(f.y, ws[j].y, accs);
            accs = fmaf(f.z, ws[j].z, accs);
            accs = fmaf(f.w, ws[j].w, accs);
            const float4 a = aLDS[buf][nl * 16 + j];
            accn = fmaf(a.x, wn[j].x, accn);
            accn = fmaf(a.y, wn[j].y, accn);
            accn = fmaf(a.z, wn[j].z, accn);
            accn = fmaf(a.w, wn[j].w, accn);
        }

        const int n = base + nl;
        if (DIV) {
            const float inv = 1.0f / fmaxf(deg[n], 1.0f);
            out[n * D + c] = accs + accn * inv;
        } else {
            out[n * D + c] = accs + accn;
        }

        if (pref) {
            if (t < 64) fLDS[buf ^ 1][t]      = fnx;
            else        aLDS[buf ^ 1][t - 64] = anx;
        }
        __syncthreads();
    }
}

// fallback scatter (tiny-ws path)
__global__ __launch_bounds__(256) void sage_scatter(
    const float* __restrict__ feat,
    const int*   __restrict__ src,
    const int*   __restrict__ dst,
    float*       __restrict__ agg,
    float*       __restrict__ deg)
{
    const int gtid = blockIdx.x * blockDim.x + threadIdx.x;
    const int edge = gtid >> 6;
    const int lane = gtid & 63;
    if (edge >= N_EDGES) return;
    const int s = src[edge];
    const int d = dst[edge];
    atomicAdd(&agg[d * D + lane], feat[s * D + lane]);
    if (lane == 0) atomicAdd(&deg[d], 1.0f);
}

extern "C" void kernel_launch(void* const* d_in, const int* in_sizes, int n_in,
                              void* d_out, int out_size, void* d_ws, size_t ws_size,
                              hipStream_t stream) {
    const float* feat = (const float*)d_in[0];
    const int*   src  = (const int*)d_in[1];
    const int*   dst  = (const int*)d_in[2];
    const float* Ws   = (const float*)d_in[3];
    const float* Wn   = (const float*)d_in[4];
    float* out = (float*)d_out;
    char*  ws  = (char*)d_ws;

    if (ws_size >= WS_NEED) {
        int* packed = (int*)(ws + WS_PACKED);
        int* cnt    = (int*)(ws + WS_CNT);
        int* off    = (int*)(ws + WS_OFF);
        int* curpad = (int*)(ws + WS_CURPAD);

        hipMemsetAsync(cnt, 0, (size_t)NIDX * sizeof(int), stream);

        k_hist     <<<64,          256,  0, stream>>>(dst, cnt);
        k_scan     <<<1,           1024, 0, stream>>>(cnt, off, curpad);
        k_partition<<<PART_BLOCKS, 256,  0, stream>>>(src, dst, curpad, packed);
        k_agg      <<<NB,          512,  0, stream>>>(feat, off, cnt, packed, out);

        sage_update<false><<<UPD_BLOCKS, 256, 0, stream>>>(
            feat, Ws, Wn, nullptr, out);
    } else {
        float* deg = (float*)(ws + WS_DEG);
        hipMemsetAsync(out, 0, (size_t)N_NODES * D * sizeof(float), stream);
        hipMemsetAsync(deg, 0, (size_t)N_NODES * sizeof(float), stream);
        sage_scatter<<<(N_EDGES * 64) / 256, 256, 0, stream>>>(feat, src, dst, out, deg);
        sage_update<true><<<UPD_BLOCKS, 256, 0, stream>>>(feat, Ws, Wn, deg, out);
    }
}

// Round 5
// 265.248 us; speedup vs baseline: 3.3882x; 3.3882x over previous
//
#include <hip/hip_runtime.h>

#define N_NODES 100000
#define N_EDGES 1600000
#define D 64

// ---- bucket geometry ----
#define NPB   240                          // nodes per bucket
#define NB    417                          // ceil(100000/240) -> covers 100080
#define NIDX  (NB * 8)                     // (bucket, color) regions = 3336
#define PART_BLOCKS (N_EDGES / 256)        // 6250, color = blockIdx & 7
#define CAP   8192                         // max records/bucket staged in LDS
                                           // (Poisson mean 3837, sd 62 -> 66 sigma)

// ---- update geometry: 2500 blocks x 10 passes x 4 nodes = 100000 ----
#define UPD_BLOCKS 2500
#define NPP 4
#define PASSES (N_NODES / (UPD_BLOCKS * NPP))   // 10

// ---- d_ws layout (bytes), total 7.44 MB ----
#define WS_PACKED   0u                          // int[N_EDGES]  6.40 MB
#define WS_CNTBC    (4u * N_EDGES)              // int[NIDX]
#define WS_OFFBC    (WS_CNTBC + 4u * NIDX)      // int[NIDX]
#define WS_CURPAD   (WS_OFFBC + 4u * NIDX)      // int[NIDX*16] (64B-strided)
#define WS_NODEOFF  (WS_CURPAD + 64u * NIDX)    // int[N_NODES]
#define WS_NODECNT  (WS_NODEOFF + 4u * N_NODES) // int[N_NODES]
#define WS_NEED     (WS_NODECNT + 4u * N_NODES) // 7,440,192 B
#define WS_DEG      0u                          // fallback: float[N_NODES]

// ===========================================================================
// 1) Histogram: edges per (bucket, color); color = partition-pass blockIdx&7.
// ===========================================================================
__global__ __launch_bounds__(256) void k_hist(
    const int* __restrict__ dst, int* __restrict__ cnt)
{
    __shared__ int h[NIDX];
    const int t = threadIdx.x;
    for (int i = t; i < NIDX; i += 256) h[i] = 0;
    __syncthreads();
    for (int e = blockIdx.x * 256 + t; e < N_EDGES; e += gridDim.x * 256) {
        const int d     = dst[e];
        const int color = (e >> 8) & 7;
        atomicAdd(&h[(d / NPB) * 8 + color], 1);
    }
    __syncthreads();
    for (int i = t; i < NIDX; i += 256)
        if (h[i]) atomicAdd(&cnt[i], h[i]);
}

// ===========================================================================
// 2) Exclusive scan of cnt[NIDX] -> off (bucket-major, so each bucket's
//    8 color regions are contiguous); seed padded cursors.
// ===========================================================================
__global__ __launch_bounds__(1024) void k_scan(
    const int* __restrict__ cnt, int* __restrict__ off, int* __restrict__ curpad)
{
    __shared__ int lds[1024];
    const int t = threadIdx.x;
    int v[4], s = 0;
    #pragma unroll
    for (int k = 0; k < 4; ++k) {
        const int i = t * 4 + k;
        v[k] = (i < NIDX) ? cnt[i] : 0;
        s += v[k];
    }
    lds[t] = s;
    __syncthreads();
    for (int o = 1; o < 1024; o <<= 1) {
        const int x = (t >= o) ? lds[t - o] : 0;
        __syncthreads();
        lds[t] += x;
        __syncthreads();
    }
    int excl = lds[t] - s;
    #pragma unroll
    for (int k = 0; k < 4; ++k) {
        const int i = t * 4 + k;
        if (i < NIDX) {
            off[i] = excl;
            curpad[i * 16] = excl;
            excl += v[k];
        }
    }
}

// ===========================================================================
// 3) Partition: append packed (src | dstLocal<<17) to region (bucket, b&7).
//    Sequential per-region tails -> low write amplification.
// ===========================================================================
__global__ __launch_bounds__(256) void k_partition(
    const int* __restrict__ src, const int* __restrict__ dst,
    int* __restrict__ curpad, int* __restrict__ packed)
{
    const int e = blockIdx.x * 256 + threadIdx.x;
    const int d = dst[e];
    const int b = d / NPB;
    const int dl = d - b * NPB;
    const int pos = atomicAdd(&curpad[(b * 8 + (blockIdx.x & 7)) * 16], 1);
    packed[pos] = src[e] | (dl << 17);
}

// ===========================================================================
// 4) Per-bucket CSR sort (in place): stage records in LDS, count 240 local
//    nodes, scan, scatter src back into packed in per-node order.
//    Emits global node_off/node_cnt.  Block-private 15KB write range.
// ===========================================================================
__global__ __launch_bounds__(512) void k_sortb(
    const int* __restrict__ offbc, const int* __restrict__ cntbc,
    int* packed,
    int* __restrict__ node_off, int* __restrict__ node_cnt)
{
    __shared__ int recs[CAP];        // 32 KB
    __shared__ int lcnt[256];
    __shared__ int sc[256];
    __shared__ int lcur[NPB];

    const int t      = threadIdx.x;
    const int bucket = blockIdx.x;
    const int base   = offbc[bucket * 8];
    int total = (offbc[bucket * 8 + 7] + cntbc[bucket * 8 + 7]) - base;
    if (total > CAP) total = CAP;    // unreachable for this input; guards LDS

    if (t < 256) lcnt[t] = 0;
    __syncthreads();

    for (int i = t; i < total; i += 512) {
        const int r = packed[base + i];
        recs[i] = r;
        atomicAdd(&lcnt[r >> 17], 1);
    }
    __syncthreads();

    // exclusive scan of 256 counters
    if (t < 256) sc[t] = lcnt[t];
    __syncthreads();
    for (int o = 1; o < 256; o <<= 1) {
        int x = 0;
        if (t < 256 && t >= o) x = sc[t - o];
        __syncthreads();
        if (t < 256) sc[t] += x;
        __syncthreads();
    }

    if (t < NPB) {
        const int excl = sc[t] - lcnt[t];
        lcur[t] = excl;
        const int n = bucket * NPB + t;
        if (n < N_NODES) {
            node_off[n] = base + excl;
            node_cnt[n] = lcnt[t];
        }
    }
    __syncthreads();

    for (int i = t; i < total; i += 512) {
        const int r   = recs[i];
        const int pos = atomicAdd(&lcur[r >> 17], 1);
        packed[base + pos] = r & 0x1FFFF;
    }
}

// ===========================================================================
// 5) Pull aggregation: ONE WAVE PER NODE (100K waves of TLP).
//    One coalesced record load per 64-edge chunk, shfl broadcast,
//    4 independent accumulator chains.  Writes the MEAN to out.
// ===========================================================================
__global__ __launch_bounds__(256) void k_aggregate(
    const float* __restrict__ feat,
    const int*   __restrict__ node_off,
    const int*   __restrict__ node_cnt,
    const int*   __restrict__ packed,   // per-node src lists
    float*       __restrict__ out)
{
    const int gtid = blockIdx.x * 256 + threadIdx.x;
    const int n    = gtid >> 6;
    const int lane = gtid & 63;
    if (n >= N_NODES) return;

    const int start = node_off[n];
    const int deg   = node_cnt[n];

    float a0 = 0.f, a1 = 0.f, a2 = 0.f, a3 = 0.f;
    for (int b = 0; b < deg; b += 64) {
        const int rem = deg - b;
        const int p   = packed[start + b + ((lane < rem) ? lane : 0)];
        const int m   = (rem < 64) ? rem : 64;
        int i = 0;
        for (; i + 4 <= m; i += 4) {
            const int s0 = __shfl(p, i);
            const int s1 = __shfl(p, i + 1);
            const int s2 = __shfl(p, i + 2);
            const int s3 = __shfl(p, i + 3);
            a0 += feat[s0 * D + lane];
            a1 += feat[s1 * D + lane];
            a2 += feat[s2 * D + lane];
            a3 += feat[s3 * D + lane];
        }
        for (; i < m; ++i)
            a0 += feat[__shfl(p, i) * D + lane];
    }

    const float inv = 1.0f / (float)((deg > 0) ? deg : 1);
    out[n * D + lane] = ((a0 + a1) + (a2 + a3)) * inv;
}

// ===========================================================================
// 6) Dense update (R2 structure, W in registers).  DIV only on fallback.
// ===========================================================================
template <bool DIV>
__global__ __launch_bounds__(256) void sage_update(
    const float* __restrict__ feat,
    const float* __restrict__ Ws,
    const float* __restrict__ Wn,
    const float* __restrict__ deg,
    float* out)
{
    __shared__ float4 fLDS[2][NPP * 16];
    __shared__ float4 aLDS[2][NPP * 16];

    const int t  = threadIdx.x;
    const int c  = t & 63;
    const int nl = t >> 6;

    const float4* Ws4 = (const float4*)Ws;
    const float4* Wn4 = (const float4*)Wn;
    float4 ws[16], wn[16];
    #pragma unroll
    for (int j = 0; j < 16; ++j) {
        ws[j] = Ws4[c * 16 + j];
        wn[j] = Wn4[c * 16 + j];
    }

    const int node0 = blockIdx.x * (NPP * PASSES);
    const float4* feat4 = (const float4*)feat;
    const float4* out4  = (const float4*)out;

    {
        const int b4 = node0 * 16;
        if (t < 64)        fLDS[0][t]      = feat4[b4 + t];
        else if (t < 128)  aLDS[0][t - 64] = out4[b4 + (t - 64)];
    }
    __syncthreads();

    for (int p = 0; p < PASSES; ++p) {
        const int buf  = p & 1;
        const int base = node0 + p * NPP;

        float4 fnx, anx;
        const bool pref = (p + 1 < PASSES) && (t < 128);
        if (pref) {
            const int b4 = (node0 + (p + 1) * NPP) * 16;
            if (t < 64) fnx = feat4[b4 + t];
            else        anx = out4[b4 + (t - 64)];
        }

        float accs = 0.0f, accn = 0.0f;
        #pragma unroll
        for (int j = 0; j < 16; ++j) {
            const float4 f = fLDS[buf][nl * 16 + j];
            accs = fmaf(f.x, ws[j].x, accs);
            accs = fmaf(f.y, ws[j].y, accs);
            accs = fmaf(f.z, ws[j].z, accs);
            accs = fmaf(f.w, ws[j].w, accs);
            const float4 a = aLDS[buf][nl * 16 + j];
            accn = fmaf(a.x, wn[j].x, accn);
            accn = fmaf(a.y, wn[j].y, accn);
            accn = fmaf(a.z, wn[j].z, accn);
            accn = fmaf(a.w, wn[j].w, accn);
        }

        const int n = base + nl;
        if (DIV) {
            const float inv = 1.0f / fmaxf(deg[n], 1.0f);
            out[n * D + c] = accs + accn * inv;
        } else {
            out[n * D + c] = accs + accn;
        }

        if (pref) {
            if (t < 64) fLDS[buf ^ 1][t]      = fnx;
            else        aLDS[buf ^ 1][t - 64] = anx;
        }
        __syncthreads();
    }
}

// fallback scatter (tiny-ws path)
__global__ __launch_bounds__(256) void sage_scatter(
    const float* __restrict__ feat,
    const int*   __restrict__ src,
    const int*   __restrict__ dst,
    float*       __restrict__ agg,
    float*       __restrict__ deg)
{
    const int gtid = blockIdx.x * blockDim.x + threadIdx.x;
    const int edge = gtid >> 6;
    const int lane = gtid & 63;
    if (edge >= N_EDGES) return;
    const int s = src[edge];
    const int d = dst[edge];
    atomicAdd(&agg[d * D + lane], feat[s * D + lane]);
    if (lane == 0) atomicAdd(&deg[d], 1.0f);
}

extern "C" void kernel_launch(void* const* d_in, const int* in_sizes, int n_in,
                              void* d_out, int out_size, void* d_ws, size_t ws_size,
                              hipStream_t stream) {
    const float* feat = (const float*)d_in[0];
    const int*   src  = (const int*)d_in[1];
    const int*   dst  = (const int*)d_in[2];
    const float* Ws   = (const float*)d_in[3];
    const float* Wn   = (const float*)d_in[4];
    float* out = (float*)d_out;
    char*  ws  = (char*)d_ws;

    if (ws_size >= WS_NEED) {
        int* packed  = (int*)(ws + WS_PACKED);
        int* cntbc   = (int*)(ws + WS_CNTBC);
        int* offbc   = (int*)(ws + WS_OFFBC);
        int* curpad  = (int*)(ws + WS_CURPAD);
        int* noff    = (int*)(ws + WS_NODEOFF);
        int* ncnt    = (int*)(ws + WS_NODECNT);

        hipMemsetAsync(cntbc, 0, (size_t)NIDX * sizeof(int), stream);

        k_hist     <<<64,          256,  0, stream>>>(dst, cntbc);
        k_scan     <<<1,           1024, 0, stream>>>(cntbc, offbc, curpad);
        k_partition<<<PART_BLOCKS, 256,  0, stream>>>(src, dst, curpad, packed);
        k_sortb    <<<NB,          512,  0, stream>>>(offbc, cntbc, packed, noff, ncnt);
        k_aggregate<<<(N_NODES * 64 + 255) / 256, 256, 0, stream>>>(
            feat, noff, ncnt, packed, out);

        sage_update<false><<<UPD_BLOCKS, 256, 0, stream>>>(
            feat, Ws, Wn, nullptr, out);
    } else {
        float* deg = (float*)(ws + WS_DEG);
        hipMemsetAsync(out, 0, (size_t)N_NODES * D * sizeof(float), stream);
        hipMemsetAsync(deg, 0, (size_t)N_NODES * sizeof(float), stream);
        sage_scatter<<<(N_EDGES * 64) / 256, 256, 0, stream>>>(feat, src, dst, out, deg);
        sage_update<true><<<UPD_BLOCKS, 256, 0, stream>>>(feat, Ws, Wn, deg, out);
    }
}

// Round 6
// 234.084 us; speedup vs baseline: 3.8393x; 1.1331x over previous
//
#include <hip/hip_runtime.h>

#define N_NODES 100000
#define N_EDGES 1600000
#define D 64

// ---- bucket geometry ----
#define NPB   240
#define NB    417                          // ceil(100000/240)
#define NIDX  (NB * 8)
#define PART_BLOCKS (N_EDGES / 256)        // 6250
#define CAP   8192

// ---- d_ws layout (bytes), total 7.44 MB ----
#define WS_PACKED   0u
#define WS_CNTBC    (4u * N_EDGES)
#define WS_OFFBC    (WS_CNTBC + 4u * NIDX)
#define WS_CURPAD   (WS_OFFBC + 4u * NIDX)
#define WS_NODEOFF  (WS_CURPAD + 64u * NIDX)
#define WS_NODECNT  (WS_NODEOFF + 4u * N_NODES)
#define WS_NEED     (WS_NODECNT + 4u * N_NODES)
#define WS_DEG      0u

// ===========================================================================
// 1) Histogram per (bucket, color)
// ===========================================================================
__global__ __launch_bounds__(256) void k_hist(
    const int* __restrict__ dst, int* __restrict__ cnt)
{
    __shared__ int h[NIDX];
    const int t = threadIdx.x;
    for (int i = t; i < NIDX; i += 256) h[i] = 0;
    __syncthreads();
    for (int e = blockIdx.x * 256 + t; e < N_EDGES; e += gridDim.x * 256) {
        const int d     = dst[e];
        const int color = (e >> 8) & 7;
        atomicAdd(&h[(d / NPB) * 8 + color], 1);
    }
    __syncthreads();
    for (int i = t; i < NIDX; i += 256)
        if (h[i]) atomicAdd(&cnt[i], h[i]);
}

// ===========================================================================
// 2) Exclusive scan of cnt[NIDX] -> off; seed padded cursors
// ===========================================================================
__global__ __launch_bounds__(1024) void k_scan(
    const int* __restrict__ cnt, int* __restrict__ off, int* __restrict__ curpad)
{
    __shared__ int lds[1024];
    const int t = threadIdx.x;
    int v[4], s = 0;
    #pragma unroll
    for (int k = 0; k < 4; ++k) {
        const int i = t * 4 + k;
        v[k] = (i < NIDX) ? cnt[i] : 0;
        s += v[k];
    }
    lds[t] = s;
    __syncthreads();
    for (int o = 1; o < 1024; o <<= 1) {
        const int x = (t >= o) ? lds[t - o] : 0;
        __syncthreads();
        lds[t] += x;
        __syncthreads();
    }
    int excl = lds[t] - s;
    #pragma unroll
    for (int k = 0; k < 4; ++k) {
        const int i = t * 4 + k;
        if (i < NIDX) {
            off[i] = excl;
            curpad[i * 16] = excl;
            excl += v[k];
        }
    }
}

// ===========================================================================
// 3) Partition: append packed (src | dstLocal<<17) per (bucket, color)
// ===========================================================================
__global__ __launch_bounds__(256) void k_partition(
    const int* __restrict__ src, const int* __restrict__ dst,
    int* __restrict__ curpad, int* __restrict__ packed)
{
    const int e = blockIdx.x * 256 + threadIdx.x;
    const int d = dst[e];
    const int b = d / NPB;
    const int dl = d - b * NPB;
    const int pos = atomicAdd(&curpad[(b * 8 + (blockIdx.x & 7)) * 16], 1);
    packed[pos] = src[e] | (dl << 17);
}

// ===========================================================================
// 4) Per-bucket CSR sort (in place via LDS staging)
// ===========================================================================
__global__ __launch_bounds__(512) void k_sortb(
    const int* __restrict__ offbc, const int* __restrict__ cntbc,
    int* packed,
    int* __restrict__ node_off, int* __restrict__ node_cnt)
{
    __shared__ int recs[CAP];
    __shared__ int lcnt[256];
    __shared__ int sc[256];
    __shared__ int lcur[NPB];

    const int t      = threadIdx.x;
    const int bucket = blockIdx.x;
    const int base   = offbc[bucket * 8];
    int total = (offbc[bucket * 8 + 7] + cntbc[bucket * 8 + 7]) - base;
    if (total > CAP) total = CAP;

    if (t < 256) lcnt[t] = 0;
    __syncthreads();

    for (int i = t; i < total; i += 512) {
        const int r = packed[base + i];
        recs[i] = r;
        atomicAdd(&lcnt[r >> 17], 1);
    }
    __syncthreads();

    if (t < 256) sc[t] = lcnt[t];
    __syncthreads();
    for (int o = 1; o < 256; o <<= 1) {
        int x = 0;
        if (t < 256 && t >= o) x = sc[t - o];
        __syncthreads();
        if (t < 256) sc[t] += x;
        __syncthreads();
    }

    if (t < NPB) {
        const int excl = sc[t] - lcnt[t];
        lcur[t] = excl;
        const int n = bucket * NPB + t;
        if (n < N_NODES) {
            node_off[n] = base + excl;
            node_cnt[n] = lcnt[t];
        }
    }
    __syncthreads();

    for (int i = t; i < total; i += 512) {
        const int r   = recs[i];
        const int pos = atomicAdd(&lcur[r >> 17], 1);
        packed[base + pos] = r & 0x1FFFF;
    }
}

// ===========================================================================
// 5) Pull aggregation: one wave per node (unchanged from R5)
// ===========================================================================
__global__ __launch_bounds__(256) void k_aggregate(
    const float* __restrict__ feat,
    const int*   __restrict__ node_off,
    const int*   __restrict__ node_cnt,
    const int*   __restrict__ packed,
    float*       __restrict__ out)
{
    const int gtid = blockIdx.x * 256 + threadIdx.x;
    const int n    = gtid >> 6;
    const int lane = gtid & 63;
    if (n >= N_NODES) return;

    const int start = node_off[n];
    const int deg   = node_cnt[n];

    float a0 = 0.f, a1 = 0.f, a2 = 0.f, a3 = 0.f;
    for (int b = 0; b < deg; b += 64) {
        const int rem = deg - b;
        const int p   = packed[start + b + ((lane < rem) ? lane : 0)];
        const int m   = (rem < 64) ? rem : 64;
        int i = 0;
        for (; i + 4 <= m; i += 4) {
            const int s0 = __shfl(p, i);
            const int s1 = __shfl(p, i + 1);
            const int s2 = __shfl(p, i + 2);
            const int s3 = __shfl(p, i + 3);
            a0 += feat[s0 * D + lane];
            a1 += feat[s1 * D + lane];
            a2 += feat[s2 * D + lane];
            a3 += feat[s3 * D + lane];
        }
        for (; i < m; ++i)
            a0 += feat[__shfl(p, i) * D + lane];
    }

    const float inv = 1.0f / (float)((deg > 0) ? deg : 1);
    out[n * D + lane] = ((a0 + a1) + (a2 + a3)) * inv;
}

// ===========================================================================
// 6) Dense update, NO LDS: W in registers (loaded once per wave lifetime),
//    feat/mean row broadcasts via v_readlane (VALU, compile-time lane),
//    grid-stride persistent waves, software-pipelined next-node loads.
// ===========================================================================
#define RL(v, l) __int_as_float(__builtin_amdgcn_readlane(__float_as_int(v), (l)))

__global__ __launch_bounds__(256) void k_update(
    const float* __restrict__ feat,
    const float* __restrict__ Ws,
    const float* __restrict__ Wn,
    float* out)   // holds mean on entry; overwritten with final result
{
    const int wid   = (blockIdx.x * 256 + threadIdx.x) >> 6;
    const int lane  = threadIdx.x & 63;
    const int nwave = (gridDim.x * 256) >> 6;

    // Each lane holds its output column's W rows: Ws[lane][:], Wn[lane][:]
    const float4* Ws4 = (const float4*)Ws;
    const float4* Wn4 = (const float4*)Wn;
    float4 ws[16], wn[16];
    #pragma unroll
    for (int j = 0; j < 16; ++j) {
        ws[j] = Ws4[lane * 16 + j];
        wn[j] = Wn4[lane * 16 + j];
    }

    int n = wid;
    if (n >= N_NODES) return;
    float f = feat[n * D + lane];
    float a = out[n * D + lane];

    for (; n < N_NODES; ) {
        const int nn = n + nwave;
        float fnx = 0.f, anx = 0.f;
        if (nn < N_NODES) {                 // prefetch next node's rows
            fnx = feat[nn * D + lane];
            anx = out[nn * D + lane];
        }

        float s0 = 0.f, s1 = 0.f, m0 = 0.f, m1 = 0.f;
        #pragma unroll
        for (int j = 0; j < 16; ++j) {
            const float4 w_s = ws[j];
            const float4 w_n = wn[j];
            const float f0 = RL(f, 4 * j + 0);
            const float f1 = RL(f, 4 * j + 1);
            const float f2 = RL(f, 4 * j + 2);
            const float f3 = RL(f, 4 * j + 3);
            s0 = fmaf(f0, w_s.x, s0);
            s1 = fmaf(f1, w_s.y, s1);
            s0 = fmaf(f2, w_s.z, s0);
            s1 = fmaf(f3, w_s.w, s1);
            const float a0 = RL(a, 4 * j + 0);
            const float a1 = RL(a, 4 * j + 1);
            const float a2 = RL(a, 4 * j + 2);
            const float a3 = RL(a, 4 * j + 3);
            m0 = fmaf(a0, w_n.x, m0);
            m1 = fmaf(a1, w_n.y, m1);
            m0 = fmaf(a2, w_n.z, m0);
            m1 = fmaf(a3, w_n.w, m1);
        }

        out[n * D + lane] = (s0 + s1) + (m0 + m1);
        n = nn;
        f = fnx;
        a = anx;
    }
}

// ===========================================================================
// fallback path (tiny-ws): R2 scatter + LDS-broadcast update with deg divide
// ===========================================================================
__global__ __launch_bounds__(256) void sage_scatter(
    const float* __restrict__ feat,
    const int*   __restrict__ src,
    const int*   __restrict__ dst,
    float*       __restrict__ agg,
    float*       __restrict__ deg)
{
    const int gtid = blockIdx.x * blockDim.x + threadIdx.x;
    const int edge = gtid >> 6;
    const int lane = gtid & 63;
    if (edge >= N_EDGES) return;
    const int s = src[edge];
    const int d = dst[edge];
    atomicAdd(&agg[d * D + lane], feat[s * D + lane]);
    if (lane == 0) atomicAdd(&deg[d], 1.0f);
}

__global__ __launch_bounds__(256) void k_update_div(
    const float* __restrict__ feat,
    const float* __restrict__ Ws,
    const float* __restrict__ Wn,
    const float* __restrict__ deg,
    float* out)
{
    const int wid   = (blockIdx.x * 256 + threadIdx.x) >> 6;
    const int lane  = threadIdx.x & 63;
    const int nwave = (gridDim.x * 256) >> 6;

    const float4* Ws4 = (const float4*)Ws;
    const float4* Wn4 = (const float4*)Wn;
    float4 ws[16], wn[16];
    #pragma unroll
    for (int j = 0; j < 16; ++j) {
        ws[j] = Ws4[lane * 16 + j];
        wn[j] = Wn4[lane * 16 + j];
    }

    for (int n = wid; n < N_NODES; n += nwave) {
        const float f = feat[n * D + lane];
        const float a = out[n * D + lane] / fmaxf(deg[n], 1.0f);
        float s0 = 0.f, s1 = 0.f, m0 = 0.f, m1 = 0.f;
        #pragma unroll
        for (int j = 0; j < 16; ++j) {
            const float4 w_s = ws[j];
            const float4 w_n = wn[j];
            s0 = fmaf(RL(f, 4 * j + 0), w_s.x, s0);
            s1 = fmaf(RL(f, 4 * j + 1), w_s.y, s1);
            s0 = fmaf(RL(f, 4 * j + 2), w_s.z, s0);
            s1 = fmaf(RL(f, 4 * j + 3), w_s.w, s1);
            m0 = fmaf(RL(a, 4 * j + 0), w_n.x, m0);
            m1 = fmaf(RL(a, 4 * j + 1), w_n.y, m1);
            m0 = fmaf(RL(a, 4 * j + 2), w_n.z, m0);
            m1 = fmaf(RL(a, 4 * j + 3), w_n.w, m1);
        }
        out[n * D + lane] = (s0 + s1) + (m0 + m1);
    }
}

extern "C" void kernel_launch(void* const* d_in, const int* in_sizes, int n_in,
                              void* d_out, int out_size, void* d_ws, size_t ws_size,
                              hipStream_t stream) {
    const float* feat = (const float*)d_in[0];
    const int*   src  = (const int*)d_in[1];
    const int*   dst  = (const int*)d_in[2];
    const float* Ws   = (const float*)d_in[3];
    const float* Wn   = (const float*)d_in[4];
    float* out = (float*)d_out;
    char*  ws  = (char*)d_ws;

    if (ws_size >= WS_NEED) {
        int* packed = (int*)(ws + WS_PACKED);
        int* cntbc  = (int*)(ws + WS_CNTBC);
        int* offbc  = (int*)(ws + WS_OFFBC);
        int* curpad = (int*)(ws + WS_CURPAD);
        int* noff   = (int*)(ws + WS_NODEOFF);
        int* ncnt   = (int*)(ws + WS_NODECNT);

        hipMemsetAsync(cntbc, 0, (size_t)NIDX * sizeof(int), stream);

        k_hist     <<<64,          256,  0, stream>>>(dst, cntbc);
        k_scan     <<<1,           1024, 0, stream>>>(cntbc, offbc, curpad);
        k_partition<<<PART_BLOCKS, 256,  0, stream>>>(src, dst, curpad, packed);
        k_sortb    <<<NB,          512,  0, stream>>>(offbc, cntbc, packed, noff, ncnt);
        k_aggregate<<<(N_NODES * 64 + 255) / 256, 256, 0, stream>>>(
            feat, noff, ncnt, packed, out);
        k_update   <<<1024,        256,  0, stream>>>(feat, Ws, Wn, out);
    } else {
        float* deg = (float*)(ws + WS_DEG);
        hipMemsetAsync(out, 0, (size_t)N_NODES * D * sizeof(float), stream);
        hipMemsetAsync(deg, 0, (size_t)N_NODES * sizeof(float), stream);
        sage_scatter<<<(N_EDGES * 64) / 256, 256, 0, stream>>>(feat, src, dst, out, deg);
        k_update_div<<<1024, 256, 0, stream>>>(feat, Ws, Wn, deg, out);
    }
}

// Round 7
// 182.928 us; speedup vs baseline: 4.9129x; 1.2797x over previous
//
#include <hip/hip_runtime.h>

#define N_NODES 100000
#define N_EDGES 1600000
#define D 64

// ---- bucket geometry ----
#define NPB   240
#define NB    417                          // ceil(100000/240)
#define CAP   8192                         // k_sortb LDS capacity (mean 3837, sd 62)

// ---- partition geometry ----
#define EPB   16384                        // edges per partition block
#define PBLK  ((N_EDGES + EPB - 1) / EPB)  // 98

// ---- d_ws layout (bytes), total ~7.21 MB ----
#define WS_PACKED   0u                          // int[N_EDGES]  6.40 MB
#define WS_CNT      (4u * N_EDGES)              // int[NB]
#define WS_OFF      (WS_CNT  + 4u * NB)         // int[NB]
#define WS_GCUR     (WS_OFF  + 4u * NB)         // int[NB]
#define WS_NODEOFF  (WS_GCUR + 4u * NB)         // int[N_NODES]
#define WS_NODECNT  (WS_NODEOFF + 4u * N_NODES) // int[N_NODES]
#define WS_NEED     (WS_NODECNT + 4u * N_NODES)
#define WS_DEG      0u

// ===========================================================================
// 1) Histogram: edges per bucket (417 counters)
// ===========================================================================
__global__ __launch_bounds__(256) void k_hist(
    const int* __restrict__ dst, int* __restrict__ cnt)
{
    __shared__ int h[NB];
    const int t = threadIdx.x;
    for (int i = t; i < NB; i += 256) h[i] = 0;
    __syncthreads();
    for (int e = blockIdx.x * 256 + t; e < N_EDGES; e += gridDim.x * 256)
        atomicAdd(&h[dst[e] / NPB], 1);
    __syncthreads();
    for (int i = t; i < NB; i += 256)
        if (h[i]) atomicAdd(&cnt[i], h[i]);
}

// ===========================================================================
// 2) Exclusive scan of cnt[NB] -> off; seed global cursors
// ===========================================================================
__global__ __launch_bounds__(512) void k_scan(
    const int* __restrict__ cnt, int* __restrict__ off, int* __restrict__ gcur)
{
    __shared__ int lds[512];
    const int t = threadIdx.x;
    const int v = (t < NB) ? cnt[t] : 0;
    lds[t] = v;
    __syncthreads();
    for (int o = 1; o < 512; o <<= 1) {
        const int x = (t >= o) ? lds[t - o] : 0;
        __syncthreads();
        lds[t] += x;
        __syncthreads();
    }
    if (t < NB) {
        const int excl = lds[t] - v;
        off[t]  = excl;
        gcur[t] = excl;
    }
}

// ===========================================================================
// 3) Block-chunked partition: per-block counting sort over 417 buckets,
//    ONE global atomic per (block,bucket) chunk reservation, coalesced
//    chunk write-out (~39 records = ~2.4 full lines from one CU).
// ===========================================================================
__global__ __launch_bounds__(1024) void k_partition(
    const int* __restrict__ src, const int* __restrict__ dst,
    int* __restrict__ gcur, int* __restrict__ packed)
{
    __shared__ int recs[EPB];        // 64 KB
    __shared__ int cnt[NB];
    __shared__ int scn[512];
    __shared__ int pos[NB];
    __shared__ int cur[NB];
    __shared__ int dlt[NB];

    const int t  = threadIdx.x;
    const int e0 = blockIdx.x * EPB;
    const int nE = min(EPB, N_EDGES - e0);

    for (int i = t; i < NB; i += 1024) cnt[i] = 0;
    __syncthreads();

    // load 16 edges/thread into registers (static indices), LDS histogram
    int pk[16], bk[16];
    #pragma unroll
    for (int k = 0; k < 16; ++k) {
        const int i = t + k * 1024;              // coalesced
        if (i < nE) {
            const int d  = dst[e0 + i];
            const int b  = d / NPB;
            const int dl = d - b * NPB;
            pk[k] = src[e0 + i] | (dl << 17);
            bk[k] = b;
            atomicAdd(&cnt[b], 1);
        } else {
            bk[k] = -1;
        }
    }
    __syncthreads();

    // exclusive scan of cnt -> pos; reserve global chunk per bucket
    if (t < 512) scn[t] = (t < NB) ? cnt[t] : 0;
    __syncthreads();
    for (int o = 1; o < 512; o <<= 1) {
        int x = 0;
        if (t < 512 && t >= o) x = scn[t - o];
        __syncthreads();
        if (t < 512) scn[t] += x;
        __syncthreads();
    }
    if (t < NB) {
        const int v    = cnt[t];
        const int excl = scn[t] - v;
        pos[t] = excl;
        cur[t] = excl;
        dlt[t] = atomicAdd(&gcur[t], v);         // global chunk base
    }
    __syncthreads();

    // scatter into LDS, bucket-ordered
    #pragma unroll
    for (int k = 0; k < 16; ++k) {
        if (bk[k] >= 0) {
            const int p = atomicAdd(&cur[bk[k]], 1);
            recs[p] = pk[k];
        }
    }
    __syncthreads();

    // coalesced chunk write-out: wave w handles buckets w, w+16, ...
    const int w    = t >> 6;
    const int lane = t & 63;
    for (int b = w; b < NB; b += 16) {
        const int n = cnt[b];
        const int o = pos[b];
        const int g = dlt[b];
        for (int i = lane; i < n; i += 64)
            packed[g + i] = recs[o + i];
    }
}

// ===========================================================================
// 4) Per-bucket CSR sort (in place via LDS staging)
// ===========================================================================
__global__ __launch_bounds__(512) void k_sortb(
    const int* __restrict__ off, const int* __restrict__ cntg,
    int* packed,
    int* __restrict__ node_off, int* __restrict__ node_cnt)
{
    __shared__ int recs[CAP];
    __shared__ int lcnt[256];
    __shared__ int sc[256];
    __shared__ int lcur[NPB];

    const int t      = threadIdx.x;
    const int bucket = blockIdx.x;
    const int base   = off[bucket];
    int total = cntg[bucket];
    if (total > CAP) total = CAP;

    if (t < 256) lcnt[t] = 0;
    __syncthreads();

    for (int i = t; i < total; i += 512) {
        const int r = packed[base + i];
        recs[i] = r;
        atomicAdd(&lcnt[r >> 17], 1);
    }
    __syncthreads();

    if (t < 256) sc[t] = lcnt[t];
    __syncthreads();
    for (int o = 1; o < 256; o <<= 1) {
        int x = 0;
        if (t < 256 && t >= o) x = sc[t - o];
        __syncthreads();
        if (t < 256) sc[t] += x;
        __syncthreads();
    }

    if (t < NPB) {
        const int excl = sc[t] - lcnt[t];
        lcur[t] = excl;
        const int n = bucket * NPB + t;
        if (n < N_NODES) {
            node_off[n] = base + excl;
            node_cnt[n] = lcnt[t];
        }
    }
    __syncthreads();

    for (int i = t; i < total; i += 512) {
        const int r   = recs[i];
        const int pos = atomicAdd(&lcur[r >> 17], 1);
        packed[base + pos] = r & 0x1FFFF;
    }
}

// ===========================================================================
// 5) Pull aggregation: one wave per node (unchanged)
// ===========================================================================
__global__ __launch_bounds__(256) void k_aggregate(
    const float* __restrict__ feat,
    const int*   __restrict__ node_off,
    const int*   __restrict__ node_cnt,
    const int*   __restrict__ packed,
    float*       __restrict__ out)
{
    const int gtid = blockIdx.x * 256 + threadIdx.x;
    const int n    = gtid >> 6;
    const int lane = gtid & 63;
    if (n >= N_NODES) return;

    const int start = node_off[n];
    const int deg   = node_cnt[n];

    float a0 = 0.f, a1 = 0.f, a2 = 0.f, a3 = 0.f;
    for (int b = 0; b < deg; b += 64) {
        const int rem = deg - b;
        const int p   = packed[start + b + ((lane < rem) ? lane : 0)];
        const int m   = (rem < 64) ? rem : 64;
        int i = 0;
        for (; i + 4 <= m; i += 4) {
            const int s0 = __shfl(p, i);
            const int s1 = __shfl(p, i + 1);
            const int s2 = __shfl(p, i + 2);
            const int s3 = __shfl(p, i + 3);
            a0 += feat[s0 * D + lane];
            a1 += feat[s1 * D + lane];
            a2 += feat[s2 * D + lane];
            a3 += feat[s3 * D + lane];
        }
        for (; i < m; ++i)
            a0 += feat[__shfl(p, i) * D + lane];
    }

    const float inv = 1.0f / (float)((deg > 0) ? deg : 1);
    out[n * D + lane] = ((a0 + a1) + (a2 + a3)) * inv;
}

// ===========================================================================
// 6) Dense update, no LDS: W in registers, v_readlane broadcasts,
//    grid-stride persistent waves (unchanged from R6)
// ===========================================================================
#define RL(v, l) __int_as_float(__builtin_amdgcn_readlane(__float_as_int(v), (l)))

__global__ __launch_bounds__(256) void k_update(
    const float* __restrict__ feat,
    const float* __restrict__ Ws,
    const float* __restrict__ Wn,
    float* out)
{
    const int wid   = (blockIdx.x * 256 + threadIdx.x) >> 6;
    const int lane  = threadIdx.x & 63;
    const int nwave = (gridDim.x * 256) >> 6;

    const float4* Ws4 = (const float4*)Ws;
    const float4* Wn4 = (const float4*)Wn;
    float4 ws[16], wn[16];
    #pragma unroll
    for (int j = 0; j < 16; ++j) {
        ws[j] = Ws4[lane * 16 + j];
        wn[j] = Wn4[lane * 16 + j];
    }

    int n = wid;
    if (n >= N_NODES) return;
    float f = feat[n * D + lane];
    float a = out[n * D + lane];

    for (; n < N_NODES; ) {
        const int nn = n + nwave;
        float fnx = 0.f, anx = 0.f;
        if (nn < N_NODES) {
            fnx = feat[nn * D + lane];
            anx = out[nn * D + lane];
        }

        float s0 = 0.f, s1 = 0.f, m0 = 0.f, m1 = 0.f;
        #pragma unroll
        for (int j = 0; j < 16; ++j) {
            const float4 w_s = ws[j];
            const float4 w_n = wn[j];
            s0 = fmaf(RL(f, 4 * j + 0), w_s.x, s0);
            s1 = fmaf(RL(f, 4 * j + 1), w_s.y, s1);
            s0 = fmaf(RL(f, 4 * j + 2), w_s.z, s0);
            s1 = fmaf(RL(f, 4 * j + 3), w_s.w, s1);
            m0 = fmaf(RL(a, 4 * j + 0), w_n.x, m0);
            m1 = fmaf(RL(a, 4 * j + 1), w_n.y, m1);
            m0 = fmaf(RL(a, 4 * j + 2), w_n.z, m0);
            m1 = fmaf(RL(a, 4 * j + 3), w_n.w, m1);
        }

        out[n * D + lane] = (s0 + s1) + (m0 + m1);
        n = nn;
        f = fnx;
        a = anx;
    }
}

// ===========================================================================
// fallback path (tiny-ws)
// ===========================================================================
__global__ __launch_bounds__(256) void sage_scatter(
    const float* __restrict__ feat,
    const int*   __restrict__ src,
    const int*   __restrict__ dst,
    float*       __restrict__ agg,
    float*       __restrict__ deg)
{
    const int gtid = blockIdx.x * blockDim.x + threadIdx.x;
    const int edge = gtid >> 6;
    const int lane = gtid & 63;
    if (edge >= N_EDGES) return;
    const int s = src[edge];
    const int d = dst[edge];
    atomicAdd(&agg[d * D + lane], feat[s * D + lane]);
    if (lane == 0) atomicAdd(&deg[d], 1.0f);
}

__global__ __launch_bounds__(256) void k_update_div(
    const float* __restrict__ feat,
    const float* __restrict__ Ws,
    const float* __restrict__ Wn,
    const float* __restrict__ deg,
    float* out)
{
    const int wid   = (blockIdx.x * 256 + threadIdx.x) >> 6;
    const int lane  = threadIdx.x & 63;
    const int nwave = (gridDim.x * 256) >> 6;

    const float4* Ws4 = (const float4*)Ws;
    const float4* Wn4 = (const float4*)Wn;
    float4 ws[16], wn[16];
    #pragma unroll
    for (int j = 0; j < 16; ++j) {
        ws[j] = Ws4[lane * 16 + j];
        wn[j] = Wn4[lane * 16 + j];
    }

    for (int n = wid; n < N_NODES; n += nwave) {
        const float f = feat[n * D + lane];
        const float a = out[n * D + lane] / fmaxf(deg[n], 1.0f);
        float s0 = 0.f, s1 = 0.f, m0 = 0.f, m1 = 0.f;
        #pragma unroll
        for (int j = 0; j < 16; ++j) {
            const float4 w_s = ws[j];
            const float4 w_n = wn[j];
            s0 = fmaf(RL(f, 4 * j + 0), w_s.x, s0);
            s1 = fmaf(RL(f, 4 * j + 1), w_s.y, s1);
            s0 = fmaf(RL(f, 4 * j + 2), w_s.z, s0);
            s1 = fmaf(RL(f, 4 * j + 3), w_s.w, s1);
            m0 = fmaf(RL(a, 4 * j + 0), w_n.x, m0);
            m1 = fmaf(RL(a, 4 * j + 1), w_n.y, m1);
            m0 = fmaf(RL(a, 4 * j + 2), w_n.z, m0);
            m1 = fmaf(RL(a, 4 * j + 3), w_n.w, m1);
        }
        out[n * D + lane] = (s0 + s1) + (m0 + m1);
    }
}

extern "C" void kernel_launch(void* const* d_in, const int* in_sizes, int n_in,
                              void* d_out, int out_size, void* d_ws, size_t ws_size,
                              hipStream_t stream) {
    const float* feat = (const float*)d_in[0];
    const int*   src  = (const int*)d_in[1];
    const int*   dst  = (const int*)d_in[2];
    const float* Ws   = (const float*)d_in[3];
    const float* Wn   = (const float*)d_in[4];
    float* out = (float*)d_out;
    char*  ws  = (char*)d_ws;

    if (ws_size >= WS_NEED) {
        int* packed = (int*)(ws + WS_PACKED);
        int* cnt    = (int*)(ws + WS_CNT);
        int* off    = (int*)(ws + WS_OFF);
        int* gcur   = (int*)(ws + WS_GCUR);
        int* noff   = (int*)(ws + WS_NODEOFF);
        int* ncnt   = (int*)(ws + WS_NODECNT);

        hipMemsetAsync(cnt, 0, (size_t)NB * sizeof(int), stream);

        k_hist     <<<64,   256,  0, stream>>>(dst, cnt);
        k_scan     <<<1,    512,  0, stream>>>(cnt, off, gcur);
        k_partition<<<PBLK, 1024, 0, stream>>>(src, dst, gcur, packed);
        k_sortb    <<<NB,   512,  0, stream>>>(off, cnt, packed, noff, ncnt);
        k_aggregate<<<(N_NODES * 64 + 255) / 256, 256, 0, stream>>>(
            feat, noff, ncnt, packed, out);
        k_update   <<<1024, 256,  0, stream>>>(feat, Ws, Wn, out);
    } else {
        float* deg = (float*)(ws + WS_DEG);
        hipMemsetAsync(out, 0, (size_t)N_NODES * D * sizeof(float), stream);
        hipMemsetAsync(deg, 0, (size_t)N_NODES * sizeof(float), stream);
        sage_scatter<<<(N_EDGES * 64) / 256, 256, 0, stream>>>(feat, src, dst, out, deg);
        k_update_div<<<1024, 256, 0, stream>>>(feat, Ws, Wn, deg, out);
    }
}

// Round 8
// 171.430 us; speedup vs baseline: 5.2425x; 1.0671x over previous
//
#include <hip/hip_runtime.h>

#define N_NODES 100000
#define N_EDGES 1600000
#define D 64

// ---- bucket geometry ----
#define NPB   240
#define NB    417                          // ceil(100000/240)
#define CAP   8192                         // k_sortb LDS capacity (mean 3837, sd 62)

// ---- partition geometry ----
#define EPB   16384
#define PBLK  ((N_EDGES + EPB - 1) / EPB)  // 98

// ---- ws layout tier 2 (bf16 gather), ~20.0 MB ----
#define W2_FB16     0u                           // ushort[N_NODES*D] 12.8 MB
#define W2_PACKED   12800000u                    // int[N_EDGES] 6.4 MB
#define W2_CNT      (W2_PACKED + 4u * N_EDGES)
#define W2_OFF      (W2_CNT  + 4u * NB)
#define W2_GCUR     (W2_OFF  + 4u * NB)
#define W2_NODEOFF  (W2_GCUR + 4u * NB)
#define W2_NODECNT  (W2_NODEOFF + 4u * N_NODES)
#define W2_NEED     (W2_NODECNT + 4u * N_NODES)  // 20,005,004

// ---- ws layout tier 1 (fp32 gather, R7), ~7.21 MB ----
#define W1_PACKED   0u
#define W1_CNT      (4u * N_EDGES)
#define W1_OFF      (W1_CNT  + 4u * NB)
#define W1_GCUR     (W1_OFF  + 4u * NB)
#define W1_NODEOFF  (W1_GCUR + 4u * NB)
#define W1_NODECNT  (W1_NODEOFF + 4u * N_NODES)
#define W1_NEED     (W1_NODECNT + 4u * N_NODES)

// ===========================================================================
// 0) feat fp32 -> bf16 (round-to-nearest-even), vectorized
// ===========================================================================
__global__ __launch_bounds__(256) void k_tobf16(
    const float* __restrict__ feat, unsigned int* __restrict__ fb16)
{
    // each thread: 8 floats -> 4 packed uints
    const int total = N_NODES * D / 8;     // 800000
    for (int i = blockIdx.x * 256 + threadIdx.x; i < total; i += gridDim.x * 256) {
        const float4 x = ((const float4*)feat)[i * 2];
        const float4 y = ((const float4*)feat)[i * 2 + 1];
        const float v[8] = {x.x, x.y, x.z, x.w, y.x, y.y, y.z, y.w};
        unsigned int o[4];
        #pragma unroll
        for (int j = 0; j < 4; ++j) {
            unsigned int lo = __float_as_uint(v[2 * j]);
            unsigned int hi = __float_as_uint(v[2 * j + 1]);
            lo = (lo + 0x7FFFu + ((lo >> 16) & 1)) >> 16;
            hi = (hi + 0x7FFFu + ((hi >> 16) & 1)) & 0xFFFF0000u;
            o[j] = lo | hi;
        }
        ((uint4*)fb16)[i] = make_uint4(o[0], o[1], o[2], o[3]);
    }
}

// ===========================================================================
// 1) Histogram: edges per bucket
// ===========================================================================
__global__ __launch_bounds__(256) void k_hist(
    const int* __restrict__ dst, int* __restrict__ cnt)
{
    __shared__ int h[NB];
    const int t = threadIdx.x;
    for (int i = t; i < NB; i += 256) h[i] = 0;
    __syncthreads();
    for (int e = blockIdx.x * 256 + t; e < N_EDGES; e += gridDim.x * 256)
        atomicAdd(&h[dst[e] / NPB], 1);
    __syncthreads();
    for (int i = t; i < NB; i += 256)
        if (h[i]) atomicAdd(&cnt[i], h[i]);
}

// ===========================================================================
// 2) Exclusive scan of cnt[NB] -> off; seed global cursors
// ===========================================================================
__global__ __launch_bounds__(512) void k_scan(
    const int* __restrict__ cnt, int* __restrict__ off, int* __restrict__ gcur)
{
    __shared__ int lds[512];
    const int t = threadIdx.x;
    const int v = (t < NB) ? cnt[t] : 0;
    lds[t] = v;
    __syncthreads();
    for (int o = 1; o < 512; o <<= 1) {
        const int x = (t >= o) ? lds[t - o] : 0;
        __syncthreads();
        lds[t] += x;
        __syncthreads();
    }
    if (t < NB) {
        const int excl = lds[t] - v;
        off[t]  = excl;
        gcur[t] = excl;
    }
}

// ===========================================================================
// 3) Block-chunked partition (R7)
// ===========================================================================
__global__ __launch_bounds__(1024) void k_partition(
    const int* __restrict__ src, const int* __restrict__ dst,
    int* __restrict__ gcur, int* __restrict__ packed)
{
    __shared__ int recs[EPB];
    __shared__ int cnt[NB];
    __shared__ int scn[512];
    __shared__ int pos[NB];
    __shared__ int cur[NB];
    __shared__ int dlt[NB];

    const int t  = threadIdx.x;
    const int e0 = blockIdx.x * EPB;
    const int nE = min(EPB, N_EDGES - e0);

    for (int i = t; i < NB; i += 1024) cnt[i] = 0;
    __syncthreads();

    int pk[16], bk[16];
    #pragma unroll
    for (int k = 0; k < 16; ++k) {
        const int i = t + k * 1024;
        if (i < nE) {
            const int d  = dst[e0 + i];
            const int b  = d / NPB;
            const int dl = d - b * NPB;
            pk[k] = src[e0 + i] | (dl << 17);
            bk[k] = b;
            atomicAdd(&cnt[b], 1);
        } else {
            bk[k] = -1;
        }
    }
    __syncthreads();

    if (t < 512) scn[t] = (t < NB) ? cnt[t] : 0;
    __syncthreads();
    for (int o = 1; o < 512; o <<= 1) {
        int x = 0;
        if (t < 512 && t >= o) x = scn[t - o];
        __syncthreads();
        if (t < 512) scn[t] += x;
        __syncthreads();
    }
    if (t < NB) {
        const int v    = cnt[t];
        const int excl = scn[t] - v;
        pos[t] = excl;
        cur[t] = excl;
        dlt[t] = atomicAdd(&gcur[t], v);
    }
    __syncthreads();

    #pragma unroll
    for (int k = 0; k < 16; ++k) {
        if (bk[k] >= 0) {
            const int p = atomicAdd(&cur[bk[k]], 1);
            recs[p] = pk[k];
        }
    }
    __syncthreads();

    const int w    = t >> 6;
    const int lane = t & 63;
    for (int b = w; b < NB; b += 16) {
        const int n = cnt[b];
        const int o = pos[b];
        const int g = dlt[b];
        for (int i = lane; i < n; i += 64)
            packed[g + i] = recs[o + i];
    }
}

// ===========================================================================
// 4) Per-bucket CSR sort (in place via LDS staging)
// ===========================================================================
__global__ __launch_bounds__(512) void k_sortb(
    const int* __restrict__ off, const int* __restrict__ cntg,
    int* packed,
    int* __restrict__ node_off, int* __restrict__ node_cnt)
{
    __shared__ int recs[CAP];
    __shared__ int lcnt[256];
    __shared__ int sc[256];
    __shared__ int lcur[NPB];

    const int t      = threadIdx.x;
    const int bucket = blockIdx.x;
    const int base   = off[bucket];
    int total = cntg[bucket];
    if (total > CAP) total = CAP;

    if (t < 256) lcnt[t] = 0;
    __syncthreads();

    for (int i = t; i < total; i += 512) {
        const int r = packed[base + i];
        recs[i] = r;
        atomicAdd(&lcnt[r >> 17], 1);
    }
    __syncthreads();

    if (t < 256) sc[t] = lcnt[t];
    __syncthreads();
    for (int o = 1; o < 256; o <<= 1) {
        int x = 0;
        if (t < 256 && t >= o) x = sc[t - o];
        __syncthreads();
        if (t < 256) sc[t] += x;
        __syncthreads();
    }

    if (t < NPB) {
        const int excl = sc[t] - lcnt[t];
        lcur[t] = excl;
        const int n = bucket * NPB + t;
        if (n < N_NODES) {
            node_off[n] = base + excl;
            node_cnt[n] = lcnt[t];
        }
    }
    __syncthreads();

    for (int i = t; i < total; i += 512) {
        const int r   = recs[i];
        const int pos = atomicAdd(&lcur[r >> 17], 1);
        packed[base + pos] = r & 0x1FFFF;
    }
}

// ===========================================================================
// 5a) Pull aggregation from BF16 feat: one wave per node.
//     16B/lane uint4 loads -> 8 rows per wave-load instruction.
//     Lane l handles edge (g + l>>3), columns (l&7)*8 .. +7.
//     fp32 accumulate; 3-step shfl_xor reduce; lanes 0-7 store the row.
// ===========================================================================
__global__ __launch_bounds__(256) void k_agg_bf16(
    const unsigned int* __restrict__ fb16,
    const int* __restrict__ node_off,
    const int* __restrict__ node_cnt,
    const int* __restrict__ packed,
    float* __restrict__ out)
{
    const int gtid = blockIdx.x * 256 + threadIdx.x;
    const int n    = gtid >> 6;
    const int lane = gtid & 63;
    if (n >= N_NODES) return;

    const int start = node_off[n];
    const int deg   = node_cnt[n];
    const int sub   = lane >> 3;       // edge slot within group of 8
    const int chunk = lane & 7;        // 16B chunk of the 128B row

    float a0 = 0.f, a1 = 0.f, a2 = 0.f, a3 = 0.f;
    float a4 = 0.f, a5 = 0.f, a6 = 0.f, a7 = 0.f;

    for (int b = 0; b < deg; b += 64) {
        const int rem = deg - b;
        const int p   = packed[start + b + ((lane < rem) ? lane : 0)];
        const int m   = (rem < 64) ? rem : 64;
        for (int g = 0; g < m; g += 8) {
            const int  e     = g + sub;
            const int  s     = __shfl(p, (e < m) ? e : 0);
            const bool valid = (e < m);
            const uint4 v = ((const uint4*)fb16)[s * 8 + chunk];
            if (valid) {
                a0 += __uint_as_float(v.x << 16);
                a1 += __uint_as_float(v.x & 0xFFFF0000u);
                a2 += __uint_as_float(v.y << 16);
                a3 += __uint_as_float(v.y & 0xFFFF0000u);
                a4 += __uint_as_float(v.z << 16);
                a5 += __uint_as_float(v.z & 0xFFFF0000u);
                a6 += __uint_as_float(v.w << 16);
                a7 += __uint_as_float(v.w & 0xFFFF0000u);
            }
        }
    }

    // reduce across the 8 edge-slot groups (lanes l, l^8, l^16, ... same cols)
    #pragma unroll
    for (int mask = 8; mask <= 32; mask <<= 1) {
        a0 += __shfl_xor(a0, mask);
        a1 += __shfl_xor(a1, mask);
        a2 += __shfl_xor(a2, mask);
        a3 += __shfl_xor(a3, mask);
        a4 += __shfl_xor(a4, mask);
        a5 += __shfl_xor(a5, mask);
        a6 += __shfl_xor(a6, mask);
        a7 += __shfl_xor(a7, mask);
    }

    if (lane < 8) {
        const float inv = 1.0f / (float)((deg > 0) ? deg : 1);
        float4* o = (float4*)(out + (size_t)n * D + lane * 8);
        o[0] = make_float4(a0 * inv, a1 * inv, a2 * inv, a3 * inv);
        o[1] = make_float4(a4 * inv, a5 * inv, a6 * inv, a7 * inv);
    }
}

// ===========================================================================
// 5b) fp32 pull aggregation (tier-1 fallback, R7)
// ===========================================================================
__global__ __launch_bounds__(256) void k_aggregate(
    const float* __restrict__ feat,
    const int*   __restrict__ node_off,
    const int*   __restrict__ node_cnt,
    const int*   __restrict__ packed,
    float*       __restrict__ out)
{
    const int gtid = blockIdx.x * 256 + threadIdx.x;
    const int n    = gtid >> 6;
    const int lane = gtid & 63;
    if (n >= N_NODES) return;

    const int start = node_off[n];
    const int deg   = node_cnt[n];

    float a0 = 0.f, a1 = 0.f, a2 = 0.f, a3 = 0.f;
    for (int b = 0; b < deg; b += 64) {
        const int rem = deg - b;
        const int p   = packed[start + b + ((lane < rem) ? lane : 0)];
        const int m   = (rem < 64) ? rem : 64;
        int i = 0;
        for (; i + 4 <= m; i += 4) {
            a0 += feat[__shfl(p, i)     * D + lane];
            a1 += feat[__shfl(p, i + 1) * D + lane];
            a2 += feat[__shfl(p, i + 2) * D + lane];
            a3 += feat[__shfl(p, i + 3) * D + lane];
        }
        for (; i < m; ++i)
            a0 += feat[__shfl(p, i) * D + lane];
    }

    const float inv = 1.0f / (float)((deg > 0) ? deg : 1);
    out[n * D + lane] = ((a0 + a1) + (a2 + a3)) * inv;
}

// ===========================================================================
// 6) Dense update, no LDS (R6): W in registers, v_readlane broadcasts
// ===========================================================================
#define RL(v, l) __int_as_float(__builtin_amdgcn_readlane(__float_as_int(v), (l)))

__global__ __launch_bounds__(256) void k_update(
    const float* __restrict__ feat,
    const float* __restrict__ Ws,
    const float* __restrict__ Wn,
    float* out)
{
    const int wid   = (blockIdx.x * 256 + threadIdx.x) >> 6;
    const int lane  = threadIdx.x & 63;
    const int nwave = (gridDim.x * 256) >> 6;

    const float4* Ws4 = (const float4*)Ws;
    const float4* Wn4 = (const float4*)Wn;
    float4 ws[16], wn[16];
    #pragma unroll
    for (int j = 0; j < 16; ++j) {
        ws[j] = Ws4[lane * 16 + j];
        wn[j] = Wn4[lane * 16 + j];
    }

    int n = wid;
    if (n >= N_NODES) return;
    float f = feat[n * D + lane];
    float a = out[n * D + lane];

    for (; n < N_NODES; ) {
        const int nn = n + nwave;
        float fnx = 0.f, anx = 0.f;
        if (nn < N_NODES) {
            fnx = feat[nn * D + lane];
            anx = out[nn * D + lane];
        }

        float s0 = 0.f, s1 = 0.f, m0 = 0.f, m1 = 0.f;
        #pragma unroll
        for (int j = 0; j < 16; ++j) {
            const float4 w_s = ws[j];
            const float4 w_n = wn[j];
            s0 = fmaf(RL(f, 4 * j + 0), w_s.x, s0);
            s1 = fmaf(RL(f, 4 * j + 1), w_s.y, s1);
            s0 = fmaf(RL(f, 4 * j + 2), w_s.z, s0);
            s1 = fmaf(RL(f, 4 * j + 3), w_s.w, s1);
            m0 = fmaf(RL(a, 4 * j + 0), w_n.x, m0);
            m1 = fmaf(RL(a, 4 * j + 1), w_n.y, m1);
            m0 = fmaf(RL(a, 4 * j + 2), w_n.z, m0);
            m1 = fmaf(RL(a, 4 * j + 3), w_n.w, m1);
        }

        out[n * D + lane] = (s0 + s1) + (m0 + m1);
        n = nn;
        f = fnx;
        a = anx;
    }
}

// ===========================================================================
// tier-0 fallback (tiny ws)
// ===========================================================================
__global__ __launch_bounds__(256) void sage_scatter(
    const float* __restrict__ feat,
    const int*   __restrict__ src,
    const int*   __restrict__ dst,
    float*       __restrict__ agg,
    float*       __restrict__ deg)
{
    const int gtid = blockIdx.x * blockDim.x + threadIdx.x;
    const int edge = gtid >> 6;
    const int lane = gtid & 63;
    if (edge >= N_EDGES) return;
    const int s = src[edge];
    const int d = dst[edge];
    atomicAdd(&agg[d * D + lane], feat[s * D + lane]);
    if (lane == 0) atomicAdd(&deg[d], 1.0f);
}

__global__ __launch_bounds__(256) void k_update_div(
    const float* __restrict__ feat,
    const float* __restrict__ Ws,
    const float* __restrict__ Wn,
    const float* __restrict__ deg,
    float* out)
{
    const int wid   = (blockIdx.x * 256 + threadIdx.x) >> 6;
    const int lane  = threadIdx.x & 63;
    const int nwave = (gridDim.x * 256) >> 6;

    const float4* Ws4 = (const float4*)Ws;
    const float4* Wn4 = (const float4*)Wn;
    float4 ws[16], wn[16];
    #pragma unroll
    for (int j = 0; j < 16; ++j) {
        ws[j] = Ws4[lane * 16 + j];
        wn[j] = Wn4[lane * 16 + j];
    }

    for (int n = wid; n < N_NODES; n += nwave) {
        const float f = feat[n * D + lane];
        const float a = out[n * D + lane] / fmaxf(deg[n], 1.0f);
        float s0 = 0.f, s1 = 0.f, m0 = 0.f, m1 = 0.f;
        #pragma unroll
        for (int j = 0; j < 16; ++j) {
            const float4 w_s = ws[j];
            const float4 w_n = wn[j];
            s0 = fmaf(RL(f, 4 * j + 0), w_s.x, s0);
            s1 = fmaf(RL(f, 4 * j + 1), w_s.y, s1);
            s0 = fmaf(RL(f, 4 * j + 2), w_s.z, s0);
            s1 = fmaf(RL(f, 4 * j + 3), w_s.w, s1);
            m0 = fmaf(RL(a, 4 * j + 0), w_n.x, m0);
            m1 = fmaf(RL(a, 4 * j + 1), w_n.y, m1);
            m0 = fmaf(RL(a, 4 * j + 2), w_n.z, m0);
            m1 = fmaf(RL(a, 4 * j + 3), w_n.w, m1);
        }
        out[n * D + lane] = (s0 + s1) + (m0 + m1);
    }
}

extern "C" void kernel_launch(void* const* d_in, const int* in_sizes, int n_in,
                              void* d_out, int out_size, void* d_ws, size_t ws_size,
                              hipStream_t stream) {
    const float* feat = (const float*)d_in[0];
    const int*   src  = (const int*)d_in[1];
    const int*   dst  = (const int*)d_in[2];
    const float* Ws   = (const float*)d_in[3];
    const float* Wn   = (const float*)d_in[4];
    float* out = (float*)d_out;
    char*  ws  = (char*)d_ws;

    if (ws_size >= W2_NEED) {
        unsigned int* fb16 = (unsigned int*)(ws + W2_FB16);
        int* packed = (int*)(ws + W2_PACKED);
        int* cnt    = (int*)(ws + W2_CNT);
        int* off    = (int*)(ws + W2_OFF);
        int* gcur   = (int*)(ws + W2_GCUR);
        int* noff   = (int*)(ws + W2_NODEOFF);
        int* ncnt   = (int*)(ws + W2_NODECNT);

        hipMemsetAsync(cnt, 0, (size_t)NB * sizeof(int), stream);

        k_tobf16   <<<1024, 256,  0, stream>>>(feat, fb16);
        k_hist     <<<64,   256,  0, stream>>>(dst, cnt);
        k_scan     <<<1,    512,  0, stream>>>(cnt, off, gcur);
        k_partition<<<PBLK, 1024, 0, stream>>>(src, dst, gcur, packed);
        k_sortb    <<<NB,   512,  0, stream>>>(off, cnt, packed, noff, ncnt);
        k_agg_bf16 <<<(N_NODES * 64 + 255) / 256, 256, 0, stream>>>(
            fb16, noff, ncnt, packed, out);
        k_update   <<<1024, 256,  0, stream>>>(feat, Ws, Wn, out);
    } else if (ws_size >= W1_NEED) {
        int* packed = (int*)(ws + W1_PACKED);
        int* cnt    = (int*)(ws + W1_CNT);
        int* off    = (int*)(ws + W1_OFF);
        int* gcur   = (int*)(ws + W1_GCUR);
        int* noff   = (int*)(ws + W1_NODEOFF);
        int* ncnt   = (int*)(ws + W1_NODECNT);

        hipMemsetAsync(cnt, 0, (size_t)NB * sizeof(int), stream);

        k_hist     <<<64,   256,  0, stream>>>(dst, cnt);
        k_scan     <<<1,    512,  0, stream>>>(cnt, off, gcur);
        k_partition<<<PBLK, 1024, 0, stream>>>(src, dst, gcur, packed);
        k_sortb    <<<NB,   512,  0, stream>>>(off, cnt, packed, noff, ncnt);
        k_aggregate<<<(N_NODES * 64 + 255) / 256, 256, 0, stream>>>(
            feat, noff, ncnt, packed, out);
        k_update   <<<1024, 256,  0, stream>>>(feat, Ws, Wn, out);
    } else {
        float* deg = (float*)ws;
        hipMemsetAsync(out, 0, (size_t)N_NODES * D * sizeof(float), stream);
        hipMemsetAsync(deg, 0, (size_t)N_NODES * sizeof(float), stream);
        sage_scatter<<<(N_EDGES * 64) / 256, 256, 0, stream>>>(feat, src, dst, out, deg);
        k_update_div<<<1024, 256, 0, stream>>>(feat, Ws, Wn, deg, out);
    }
}

// Round 9
// 155.584 us; speedup vs baseline: 5.7764x; 1.1018x over previous
//
#include <hip/hip_runtime.h>

#define N_NODES 100000
#define N_EDGES 1600000
#define D 64

// ---- bucket geometry ----
#define NPB   240
#define NB    417
#define CAP   8192

// ---- partition geometry ----
#define EPB   16384
#define PBLK  ((N_EDGES + EPB - 1) / EPB)  // 98

// ---- ws layout tier 2 (bf16 gather + MFMA update), ~20.0 MB ----
#define W2_FB16     0u                           // ushort[N_NODES*D] 12.8 MB
#define W2_PACKED   12800000u                    // int[N_EDGES] 6.4 MB
#define W2_CNT      (W2_PACKED + 4u * N_EDGES)
#define W2_OFF      (W2_CNT  + 4u * NB)
#define W2_GCUR     (W2_OFF  + 4u * NB)
#define W2_NODEOFF  (W2_GCUR + 4u * NB)
#define W2_NODECNT  (W2_NODEOFF + 4u * N_NODES)
#define W2_NEED     (W2_NODECNT + 4u * N_NODES)

// ---- ws layout tier 1 (fp32, R7) ----
#define W1_PACKED   0u
#define W1_CNT      (4u * N_EDGES)
#define W1_OFF      (W1_CNT  + 4u * NB)
#define W1_GCUR     (W1_OFF  + 4u * NB)
#define W1_NODEOFF  (W1_GCUR + 4u * NB)
#define W1_NODECNT  (W1_NODEOFF + 4u * N_NODES)
#define W1_NEED     (W1_NODECNT + 4u * N_NODES)

typedef __attribute__((ext_vector_type(8))) short short8;
typedef __attribute__((ext_vector_type(4))) float f32x4;

__device__ inline unsigned int pack2bf16(float lo, float hi) {
    unsigned int ulo = __float_as_uint(lo);
    unsigned int uhi = __float_as_uint(hi);
    ulo = (ulo + 0x7FFFu + ((ulo >> 16) & 1)) >> 16;
    uhi = (uhi + 0x7FFFu + ((uhi >> 16) & 1)) & 0xFFFF0000u;
    return ulo | uhi;
}

// ===========================================================================
// 0) feat fp32 -> bf16 (RNE), vectorized
// ===========================================================================
__global__ __launch_bounds__(256) void k_tobf16(
    const float* __restrict__ feat, unsigned int* __restrict__ fb16)
{
    const int total = N_NODES * D / 8;
    for (int i = blockIdx.x * 256 + threadIdx.x; i < total; i += gridDim.x * 256) {
        const float4 x = ((const float4*)feat)[i * 2];
        const float4 y = ((const float4*)feat)[i * 2 + 1];
        uint4 o;
        o.x = pack2bf16(x.x, x.y);
        o.y = pack2bf16(x.z, x.w);
        o.z = pack2bf16(y.x, y.y);
        o.w = pack2bf16(y.z, y.w);
        ((uint4*)fb16)[i] = o;
    }
}

// ===========================================================================
// 1) Histogram: edges per bucket
// ===========================================================================
__global__ __launch_bounds__(256) void k_hist(
    const int* __restrict__ dst, int* __restrict__ cnt)
{
    __shared__ int h[NB];
    const int t = threadIdx.x;
    for (int i = t; i < NB; i += 256) h[i] = 0;
    __syncthreads();
    for (int e = blockIdx.x * 256 + t; e < N_EDGES; e += gridDim.x * 256)
        atomicAdd(&h[dst[e] / NPB], 1);
    __syncthreads();
    for (int i = t; i < NB; i += 256)
        if (h[i]) atomicAdd(&cnt[i], h[i]);
}

// ===========================================================================
// 2) Exclusive scan of cnt[NB] -> off; seed global cursors
// ===========================================================================
__global__ __launch_bounds__(512) void k_scan(
    const int* __restrict__ cnt, int* __restrict__ off, int* __restrict__ gcur)
{
    __shared__ int lds[512];
    const int t = threadIdx.x;
    const int v = (t < NB) ? cnt[t] : 0;
    lds[t] = v;
    __syncthreads();
    for (int o = 1; o < 512; o <<= 1) {
        const int x = (t >= o) ? lds[t - o] : 0;
        __syncthreads();
        lds[t] += x;
        __syncthreads();
    }
    if (t < NB) {
        const int excl = lds[t] - v;
        off[t]  = excl;
        gcur[t] = excl;
    }
}

// ===========================================================================
// 3) Block-chunked partition (R7)
// ===========================================================================
__global__ __launch_bounds__(1024) void k_partition(
    const int* __restrict__ src, const int* __restrict__ dst,
    int* __restrict__ gcur, int* __restrict__ packed)
{
    __shared__ int recs[EPB];
    __shared__ int cnt[NB];
    __shared__ int scn[512];
    __shared__ int pos[NB];
    __shared__ int cur[NB];
    __shared__ int dlt[NB];

    const int t  = threadIdx.x;
    const int e0 = blockIdx.x * EPB;
    const int nE = min(EPB, N_EDGES - e0);

    for (int i = t; i < NB; i += 1024) cnt[i] = 0;
    __syncthreads();

    int pk[16], bk[16];
    #pragma unroll
    for (int k = 0; k < 16; ++k) {
        const int i = t + k * 1024;
        if (i < nE) {
            const int d  = dst[e0 + i];
            const int b  = d / NPB;
            const int dl = d - b * NPB;
            pk[k] = src[e0 + i] | (dl << 17);
            bk[k] = b;
            atomicAdd(&cnt[b], 1);
        } else {
            bk[k] = -1;
        }
    }
    __syncthreads();

    if (t < 512) scn[t] = (t < NB) ? cnt[t] : 0;
    __syncthreads();
    for (int o = 1; o < 512; o <<= 1) {
        int x = 0;
        if (t < 512 && t >= o) x = scn[t - o];
        __syncthreads();
        if (t < 512) scn[t] += x;
        __syncthreads();
    }
    if (t < NB) {
        const int v    = cnt[t];
        const int excl = scn[t] - v;
        pos[t] = excl;
        cur[t] = excl;
        dlt[t] = atomicAdd(&gcur[t], v);
    }
    __syncthreads();

    #pragma unroll
    for (int k = 0; k < 16; ++k) {
        if (bk[k] >= 0) {
            const int p = atomicAdd(&cur[bk[k]], 1);
            recs[p] = pk[k];
        }
    }
    __syncthreads();

    const int w    = t >> 6;
    const int lane = t & 63;
    for (int b = w; b < NB; b += 16) {
        const int n = cnt[b];
        const int o = pos[b];
        const int g = dlt[b];
        for (int i = lane; i < n; i += 64)
            packed[g + i] = recs[o + i];
    }
}

// ===========================================================================
// 4) Per-bucket CSR sort (in place via LDS staging)
// ===========================================================================
__global__ __launch_bounds__(512) void k_sortb(
    const int* __restrict__ off, const int* __restrict__ cntg,
    int* packed,
    int* __restrict__ node_off, int* __restrict__ node_cnt)
{
    __shared__ int recs[CAP];
    __shared__ int lcnt[256];
    __shared__ int sc[256];
    __shared__ int lcur[NPB];

    const int t      = threadIdx.x;
    const int bucket = blockIdx.x;
    const int base   = off[bucket];
    int total = cntg[bucket];
    if (total > CAP) total = CAP;

    if (t < 256) lcnt[t] = 0;
    __syncthreads();

    for (int i = t; i < total; i += 512) {
        const int r = packed[base + i];
        recs[i] = r;
        atomicAdd(&lcnt[r >> 17], 1);
    }
    __syncthreads();

    if (t < 256) sc[t] = lcnt[t];
    __syncthreads();
    for (int o = 1; o < 256; o <<= 1) {
        int x = 0;
        if (t < 256 && t >= o) x = sc[t - o];
        __syncthreads();
        if (t < 256) sc[t] += x;
        __syncthreads();
    }

    if (t < NPB) {
        const int excl = sc[t] - lcnt[t];
        lcur[t] = excl;
        const int n = bucket * NPB + t;
        if (n < N_NODES) {
            node_off[n] = base + excl;
            node_cnt[n] = lcnt[t];
        }
    }
    __syncthreads();

    for (int i = t; i < total; i += 512) {
        const int r   = recs[i];
        const int pos = atomicAdd(&lcur[r >> 17], 1);
        packed[base + pos] = r & 0x1FFFF;
    }
}

// ===========================================================================
// 5a) BF16 pull aggregation, one wave per node.  Writes the MEAN as packed
//     bf16 into the FIRST 128B of out's row n (row-private; the update
//     kernel reads it there before overwriting the row with the result).
// ===========================================================================
__global__ __launch_bounds__(256) void k_agg_bf16(
    const unsigned int* __restrict__ fb16,
    const int* __restrict__ node_off,
    const int* __restrict__ node_cnt,
    const int* __restrict__ packed,
    float* __restrict__ out)
{
    const int gtid = blockIdx.x * 256 + threadIdx.x;
    const int n    = gtid >> 6;
    const int lane = gtid & 63;
    if (n >= N_NODES) return;

    const int start = node_off[n];
    const int deg   = node_cnt[n];
    const int sub   = lane >> 3;
    const int chunk = lane & 7;

    float a0 = 0.f, a1 = 0.f, a2 = 0.f, a3 = 0.f;
    float a4 = 0.f, a5 = 0.f, a6 = 0.f, a7 = 0.f;

    for (int b = 0; b < deg; b += 64) {
        const int rem = deg - b;
        const int p   = packed[start + b + ((lane < rem) ? lane : 0)];
        const int m   = (rem < 64) ? rem : 64;
        for (int g = 0; g < m; g += 8) {
            const int  e     = g + sub;
            const int  s     = __shfl(p, (e < m) ? e : 0);
            const bool valid = (e < m);
            const uint4 v = ((const uint4*)fb16)[s * 8 + chunk];
            if (valid) {
                a0 += __uint_as_float(v.x << 16);
                a1 += __uint_as_float(v.x & 0xFFFF0000u);
                a2 += __uint_as_float(v.y << 16);
                a3 += __uint_as_float(v.y & 0xFFFF0000u);
                a4 += __uint_as_float(v.z << 16);
                a5 += __uint_as_float(v.z & 0xFFFF0000u);
                a6 += __uint_as_float(v.w << 16);
                a7 += __uint_as_float(v.w & 0xFFFF0000u);
            }
        }
    }

    #pragma unroll
    for (int mask = 8; mask <= 32; mask <<= 1) {
        a0 += __shfl_xor(a0, mask);
        a1 += __shfl_xor(a1, mask);
        a2 += __shfl_xor(a2, mask);
        a3 += __shfl_xor(a3, mask);
        a4 += __shfl_xor(a4, mask);
        a5 += __shfl_xor(a5, mask);
        a6 += __shfl_xor(a6, mask);
        a7 += __shfl_xor(a7, mask);
    }

    if (lane < 8) {
        const float inv = 1.0f / (float)((deg > 0) ? deg : 1);
        uint4 mb;
        mb.x = pack2bf16(a0 * inv, a1 * inv);
        mb.y = pack2bf16(a2 * inv, a3 * inv);
        mb.z = pack2bf16(a4 * inv, a5 * inv);
        mb.w = pack2bf16(a6 * inv, a7 * inv);
        ((uint4*)out)[(size_t)n * 16 + lane] = mb;   // mean-bf16, first 128B of row
    }
}

// ===========================================================================
// 6a) MFMA dense update: out[n][c] = feat[n]·Ws[c] + mean[n]·Wn[c].
//     Block = 64 nodes, 4 waves x 16-node tile.  A = fb16 rows / mean-bf16
//     rows (staged in out's first 128B per row); B = bf16(W) rows (K-major,
//     contiguous).  16 MFMAs/wave into 4 C frags.  m97-verified layouts:
//     A: row=lane&15, k=(lane>>4)*8+j;  C/D: col=lane&15, row=(lane>>4)*4+r.
// ===========================================================================
__global__ __launch_bounds__(256) void k_update_mfma(
    const unsigned int* __restrict__ fb16,
    const float* __restrict__ Ws,
    const float* __restrict__ Wn,
    float* out)
{
    const int wv   = threadIdx.x >> 6;
    const int lane = threadIdx.x & 63;
    const int n0   = blockIdx.x * 64 + wv * 16;
    const int r16  = lane & 15;
    const int g    = lane >> 4;

    // B fragments: lane holds W[c][k0..k0+7] as bf16, c = nt*16+r16
    short8 bws[4][2], bwn[4][2];
    #pragma unroll
    for (int nt = 0; nt < 4; ++nt) {
        const int c = nt * 16 + r16;
        #pragma unroll
        for (int kt = 0; kt < 2; ++kt) {
            const int k0 = kt * 32 + g * 8;
            float4 w0 = *(const float4*)(Ws + c * 64 + k0);
            float4 w1 = *(const float4*)(Ws + c * 64 + k0 + 4);
            uint4 u = make_uint4(pack2bf16(w0.x, w0.y), pack2bf16(w0.z, w0.w),
                                 pack2bf16(w1.x, w1.y), pack2bf16(w1.z, w1.w));
            bws[nt][kt] = *(short8*)&u;
            w0 = *(const float4*)(Wn + c * 64 + k0);
            w1 = *(const float4*)(Wn + c * 64 + k0 + 4);
            u = make_uint4(pack2bf16(w0.x, w0.y), pack2bf16(w0.z, w0.w),
                           pack2bf16(w1.x, w1.y), pack2bf16(w1.z, w1.w));
            bwn[nt][kt] = *(short8*)&u;
        }
    }

    const int arow = n0 + r16;
    const int rc   = (arow < N_NODES) ? arow : (N_NODES - 1);

    f32x4 acc[4] = {{0.f,0.f,0.f,0.f}, {0.f,0.f,0.f,0.f},
                    {0.f,0.f,0.f,0.f}, {0.f,0.f,0.f,0.f}};

    #pragma unroll
    for (int kt = 0; kt < 2; ++kt) {
        const int k8 = kt * 4 + g;                       // (k0)/8
        const uint4 af_u = ((const uint4*)fb16)[(size_t)rc * 8 + k8];
        const uint4 am_u = ((const uint4*)out )[(size_t)rc * 16 + k8];
        const short8 af = *(const short8*)&af_u;
        const short8 am = *(const short8*)&am_u;
        #pragma unroll
        for (int nt = 0; nt < 4; ++nt) {
            acc[nt] = __builtin_amdgcn_mfma_f32_16x16x32_bf16(af, bws[nt][kt], acc[nt], 0, 0, 0);
            acc[nt] = __builtin_amdgcn_mfma_f32_16x16x32_bf16(am, bwn[nt][kt], acc[nt], 0, 0, 0);
        }
    }

    // C write (depends on all mean loads via acc -> no WAR hazard on out)
    #pragma unroll
    for (int nt = 0; nt < 4; ++nt) {
        #pragma unroll
        for (int r = 0; r < 4; ++r) {
            const int ro = n0 + g * 4 + r;
            if (ro < N_NODES)
                out[(size_t)ro * 64 + nt * 16 + r16] = acc[nt][r];
        }
    }
}

// ===========================================================================
// 5b/6b) tier-1 fp32 fallbacks (R7 structure)
// ===========================================================================
__global__ __launch_bounds__(256) void k_aggregate(
    const float* __restrict__ feat,
    const int*   __restrict__ node_off,
    const int*   __restrict__ node_cnt,
    const int*   __restrict__ packed,
    float*       __restrict__ out)
{
    const int gtid = blockIdx.x * 256 + threadIdx.x;
    const int n    = gtid >> 6;
    const int lane = gtid & 63;
    if (n >= N_NODES) return;

    const int start = node_off[n];
    const int deg   = node_cnt[n];

    float a0 = 0.f, a1 = 0.f, a2 = 0.f, a3 = 0.f;
    for (int b = 0; b < deg; b += 64) {
        const int rem = deg - b;
        const int p   = packed[start + b + ((lane < rem) ? lane : 0)];
        const int m   = (rem < 64) ? rem : 64;
        int i = 0;
        for (; i + 4 <= m; i += 4) {
            a0 += feat[__shfl(p, i)     * D + lane];
            a1 += feat[__shfl(p, i + 1) * D + lane];
            a2 += feat[__shfl(p, i + 2) * D + lane];
            a3 += feat[__shfl(p, i + 3) * D + lane];
        }
        for (; i < m; ++i)
            a0 += feat[__shfl(p, i) * D + lane];
    }

    const float inv = 1.0f / (float)((deg > 0) ? deg : 1);
    out[n * D + lane] = ((a0 + a1) + (a2 + a3)) * inv;
}

#define RL(v, l) __int_as_float(__builtin_amdgcn_readlane(__float_as_int(v), (l)))

__global__ __launch_bounds__(256) void k_update(
    const float* __restrict__ feat,
    const float* __restrict__ Ws,
    const float* __restrict__ Wn,
    float* out)
{
    const int wid   = (blockIdx.x * 256 + threadIdx.x) >> 6;
    const int lane  = threadIdx.x & 63;
    const int nwave = (gridDim.x * 256) >> 6;

    const float4* Ws4 = (const float4*)Ws;
    const float4* Wn4 = (const float4*)Wn;
    float4 ws[16], wn[16];
    #pragma unroll
    for (int j = 0; j < 16; ++j) {
        ws[j] = Ws4[lane * 16 + j];
        wn[j] = Wn4[lane * 16 + j];
    }

    for (int n = wid; n < N_NODES; n += nwave) {
        const float f = feat[n * D + lane];
        const float a = out[n * D + lane];
        float s0 = 0.f, s1 = 0.f, m0 = 0.f, m1 = 0.f;
        #pragma unroll
        for (int j = 0; j < 16; ++j) {
            const float4 w_s = ws[j];
            const float4 w_n = wn[j];
            s0 = fmaf(RL(f, 4 * j + 0), w_s.x, s0);
            s1 = fmaf(RL(f, 4 * j + 1), w_s.y, s1);
            s0 = fmaf(RL(f, 4 * j + 2), w_s.z, s0);
            s1 = fmaf(RL(f, 4 * j + 3), w_s.w, s1);
            m0 = fmaf(RL(a, 4 * j + 0), w_n.x, m0);
            m1 = fmaf(RL(a, 4 * j + 1), w_n.y, m1);
            m0 = fmaf(RL(a, 4 * j + 2), w_n.z, m0);
            m1 = fmaf(RL(a, 4 * j + 3), w_n.w, m1);
        }
        out[n * D + lane] = (s0 + s1) + (m0 + m1);
    }
}

// ===========================================================================
// tier-0 fallback (tiny ws)
// ===========================================================================
__global__ __launch_bounds__(256) void sage_scatter(
    const float* __restrict__ feat,
    const int*   __restrict__ src,
    const int*   __restrict__ dst,
    float*       __restrict__ agg,
    float*       __restrict__ deg)
{
    const int gtid = blockIdx.x * blockDim.x + threadIdx.x;
    const int edge = gtid >> 6;
    const int lane = gtid & 63;
    if (edge >= N_EDGES) return;
    const int s = src[edge];
    const int d = dst[edge];
    atomicAdd(&agg[d * D + lane], feat[s * D + lane]);
    if (lane == 0) atomicAdd(&deg[d], 1.0f);
}

__global__ __launch_bounds__(256) void k_update_div(
    const float* __restrict__ feat,
    const float* __restrict__ Ws,
    const float* __restrict__ Wn,
    const float* __restrict__ deg,
    float* out)
{
    const int wid   = (blockIdx.x * 256 + threadIdx.x) >> 6;
    const int lane  = threadIdx.x & 63;
    const int nwave = (gridDim.x * 256) >> 6;

    const float4* Ws4 = (const float4*)Ws;
    const float4* Wn4 = (const float4*)Wn;
    float4 ws[16], wn[16];
    #pragma unroll
    for (int j = 0; j < 16; ++j) {
        ws[j] = Ws4[lane * 16 + j];
        wn[j] = Wn4[lane * 16 + j];
    }

    for (int n = wid; n < N_NODES; n += nwave) {
        const float f = feat[n * D + lane];
        const float a = out[n * D + lane] / fmaxf(deg[n], 1.0f);
        float s0 = 0.f, s1 = 0.f, m0 = 0.f, m1 = 0.f;
        #pragma unroll
        for (int j = 0; j < 16; ++j) {
            const float4 w_s = ws[j];
            const float4 w_n = wn[j];
            s0 = fmaf(RL(f, 4 * j + 0), w_s.x, s0);
            s1 = fmaf(RL(f, 4 * j + 1), w_s.y, s1);
            s0 = fmaf(RL(f, 4 * j + 2), w_s.z, s0);
            s1 = fmaf(RL(f, 4 * j + 3), w_s.w, s1);
            m0 = fmaf(RL(a, 4 * j + 0), w_n.x, m0);
            m1 = fmaf(RL(a, 4 * j + 1), w_n.y, m1);
            m0 = fmaf(RL(a, 4 * j + 2), w_n.z, m0);
            m1 = fmaf(RL(a, 4 * j + 3), w_n.w, m1);
        }
        out[n * D + lane] = (s0 + s1) + (m0 + m1);
    }
}

extern "C" void kernel_launch(void* const* d_in, const int* in_sizes, int n_in,
                              void* d_out, int out_size, void* d_ws, size_t ws_size,
                              hipStream_t stream) {
    const float* feat = (const float*)d_in[0];
    const int*   src  = (const int*)d_in[1];
    const int*   dst  = (const int*)d_in[2];
    const float* Ws   = (const float*)d_in[3];
    const float* Wn   = (const float*)d_in[4];
    float* out = (float*)d_out;
    char*  ws  = (char*)d_ws;

    if (ws_size >= W2_NEED) {
        unsigned int* fb16 = (unsigned int*)(ws + W2_FB16);
        int* packed = (int*)(ws + W2_PACKED);
        int* cnt    = (int*)(ws + W2_CNT);
        int* off    = (int*)(ws + W2_OFF);
        int* gcur   = (int*)(ws + W2_GCUR);
        int* noff   = (int*)(ws + W2_NODEOFF);
        int* ncnt   = (int*)(ws + W2_NODECNT);

        hipMemsetAsync(cnt, 0, (size_t)NB * sizeof(int), stream);

        k_tobf16     <<<1024, 256,  0, stream>>>(feat, fb16);
        k_hist       <<<64,   256,  0, stream>>>(dst, cnt);
        k_scan       <<<1,    512,  0, stream>>>(cnt, off, gcur);
        k_partition  <<<PBLK, 1024, 0, stream>>>(src, dst, gcur, packed);
        k_sortb      <<<NB,   512,  0, stream>>>(off, cnt, packed, noff, ncnt);
        k_agg_bf16   <<<(N_NODES * 64 + 255) / 256, 256, 0, stream>>>(
            fb16, noff, ncnt, packed, out);
        k_update_mfma<<<(N_NODES + 63) / 64, 256, 0, stream>>>(
            fb16, Ws, Wn, out);
    } else if (ws_size >= W1_NEED) {
        int* packed = (int*)(ws + W1_PACKED);
        int* cnt    = (int*)(ws + W1_CNT);
        int* off    = (int*)(ws + W1_OFF);
        int* gcur   = (int*)(ws + W1_GCUR);
        int* noff   = (int*)(ws + W1_NODEOFF);
        int* ncnt   = (int*)(ws + W1_NODECNT);

        hipMemsetAsync(cnt, 0, (size_t)NB * sizeof(int), stream);

        k_hist     <<<64,   256,  0, stream>>>(dst, cnt);
        k_scan     <<<1,    512,  0, stream>>>(cnt, off, gcur);
        k_partition<<<PBLK, 1024, 0, stream>>>(src, dst, gcur, packed);
        k_sortb    <<<NB,   512,  0, stream>>>(off, cnt, packed, noff, ncnt);
        k_aggregate<<<(N_NODES * 64 + 255) / 256, 256, 0, stream>>>(
            feat, noff, ncnt, packed, out);
        k_update   <<<1024, 256,  0, stream>>>(feat, Ws, Wn, out);
    } else {
        float* deg = (float*)ws;
        hipMemsetAsync(out, 0, (size_t)N_NODES * D * sizeof(float), stream);
        hipMemsetAsync(deg, 0, (size_t)N_NODES * sizeof(float), stream);
        sage_scatter<<<(N_EDGES * 64) / 256, 256, 0, stream>>>(feat, src, dst, out, deg);
        k_update_div<<<1024, 256, 0, stream>>>(feat, Ws, Wn, deg, out);
    }
}

// Round 10
// 120.068 us; speedup vs baseline: 7.4850x; 1.2958x over previous
//
#include <hip/hip_runtime.h>
#include <hip/hip_fp16.h>

#define N_NODES 100000
#define N_EDGES 1600000
#define D 64

// ---- bucket geometry ----
#define NPB   240
#define NB    417
#define CAP   8192

// ---- partition geometry ----
#define EPB   16384
#define PBLK  ((N_EDGES + EPB - 1) / EPB)  // 98

// ---- ws layout tier 2 (f16 gather + MFMA update), ~20.02 MB ----
#define W2_FF16     0u                           // f16[N_NODES*D] 12.8 MB
#define W2_PACKED   12800000u                    // int[N_EDGES] 6.4 MB
#define W2_CNT      (W2_PACKED + 4u * N_EDGES)
#define W2_OFF      (W2_CNT  + 4u * NB)
#define W2_GCUR     (W2_OFF  + 4u * NB)
#define W2_NODEOFF  (W2_GCUR + 4u * NB)
#define W2_NODECNT  (W2_NODEOFF + 4u * N_NODES)
#define W2_W16      (W2_NODECNT + 4u * N_NODES)  // f16[2*64*64] = 16 KB
#define W2_NEED     (W2_W16 + 16384u)

// ---- ws layout tier 1 (fp32, R7) ----
#define W1_PACKED   0u
#define W1_CNT      (4u * N_EDGES)
#define W1_OFF      (W1_CNT  + 4u * NB)
#define W1_GCUR     (W1_OFF  + 4u * NB)
#define W1_NODEOFF  (W1_GCUR + 4u * NB)
#define W1_NODECNT  (W1_NODEOFF + 4u * N_NODES)
#define W1_NEED     (W1_NODECNT + 4u * N_NODES)

typedef __attribute__((ext_vector_type(8))) _Float16 half8;
typedef __attribute__((ext_vector_type(4))) float f32x4;

__device__ inline unsigned int h2bits(__half2 h) { return *(unsigned int*)&h; }
__device__ inline __half2 bits2h(unsigned int u) { return *(__half2*)&u; }
__device__ inline __half2 h2shfl_xor(__half2 x, int mask) {
    int i = *(int*)&x;
    i = __shfl_xor(i, mask);
    return *(__half2*)&i;
}

// ===========================================================================
// 0) Fused prep: blocks [0,1024) feat->f16; [1024,1280) dst histogram;
//    block 1280 W->f16.  All three independent.
// ===========================================================================
__global__ __launch_bounds__(256) void k_prep(
    const float* __restrict__ feat, const int* __restrict__ dst,
    const float* __restrict__ Ws, const float* __restrict__ Wn,
    unsigned int* __restrict__ ff16, int* __restrict__ cnt,
    unsigned int* __restrict__ w16)
{
    __shared__ int h[NB];
    const int bid = blockIdx.x;
    const int t   = threadIdx.x;

    if (bid < 1024) {
        const int total = N_NODES * D / 8;     // 800000 uint4 outputs
        for (int i = bid * 256 + t; i < total; i += 1024 * 256) {
            const float4 x = ((const float4*)feat)[i * 2];
            const float4 y = ((const float4*)feat)[i * 2 + 1];
            uint4 o;
            o.x = h2bits(__floats2half2_rn(x.x, x.y));
            o.y = h2bits(__floats2half2_rn(x.z, x.w));
            o.z = h2bits(__floats2half2_rn(y.x, y.y));
            o.w = h2bits(__floats2half2_rn(y.z, y.w));
            ((uint4*)ff16)[i] = o;
        }
    } else if (bid < 1280) {
        for (int i = t; i < NB; i += 256) h[i] = 0;
        __syncthreads();
        for (int e = (bid - 1024) * 256 + t; e < N_EDGES; e += 256 * 256)
            atomicAdd(&h[dst[e] / NPB], 1);
        __syncthreads();
        for (int i = t; i < NB; i += 256)
            if (h[i]) atomicAdd(&cnt[i], h[i]);
    } else {
        // W: 2 matrices x 4096 floats -> 4096 packed uints
        for (int i = t; i < 2048; i += 256)
            w16[i] = h2bits(__floats2half2_rn(Ws[2 * i], Ws[2 * i + 1]));
        for (int i = t; i < 2048; i += 256)
            w16[2048 + i] = h2bits(__floats2half2_rn(Wn[2 * i], Wn[2 * i + 1]));
    }
}

// ===========================================================================
// 2) Exclusive scan of cnt[NB] -> off; seed global cursors
// ===========================================================================
__global__ __launch_bounds__(512) void k_scan(
    const int* __restrict__ cnt, int* __restrict__ off, int* __restrict__ gcur)
{
    __shared__ int lds[512];
    const int t = threadIdx.x;
    const int v = (t < NB) ? cnt[t] : 0;
    lds[t] = v;
    __syncthreads();
    for (int o = 1; o < 512; o <<= 1) {
        const int x = (t >= o) ? lds[t - o] : 0;
        __syncthreads();
        lds[t] += x;
        __syncthreads();
    }
    if (t < NB) {
        const int excl = lds[t] - v;
        off[t]  = excl;
        gcur[t] = excl;
    }
}

// ===========================================================================
// 3) Block-chunked partition (R7)
// ===========================================================================
__global__ __launch_bounds__(1024) void k_partition(
    const int* __restrict__ src, const int* __restrict__ dst,
    int* __restrict__ gcur, int* __restrict__ packed)
{
    __shared__ int recs[EPB];
    __shared__ int cnt[NB];
    __shared__ int scn[512];
    __shared__ int pos[NB];
    __shared__ int cur[NB];
    __shared__ int dlt[NB];

    const int t  = threadIdx.x;
    const int e0 = blockIdx.x * EPB;
    const int nE = min(EPB, N_EDGES - e0);

    for (int i = t; i < NB; i += 1024) cnt[i] = 0;
    __syncthreads();

    int pk[16], bk[16];
    #pragma unroll
    for (int k = 0; k < 16; ++k) {
        const int i = t + k * 1024;
        if (i < nE) {
            const int d  = dst[e0 + i];
            const int b  = d / NPB;
            const int dl = d - b * NPB;
            pk[k] = src[e0 + i] | (dl << 17);
            bk[k] = b;
            atomicAdd(&cnt[b], 1);
        } else {
            bk[k] = -1;
        }
    }
    __syncthreads();

    if (t < 512) scn[t] = (t < NB) ? cnt[t] : 0;
    __syncthreads();
    for (int o = 1; o < 512; o <<= 1) {
        int x = 0;
        if (t < 512 && t >= o) x = scn[t - o];
        __syncthreads();
        if (t < 512) scn[t] += x;
        __syncthreads();
    }
    if (t < NB) {
        const int v    = cnt[t];
        const int excl = scn[t] - v;
        pos[t] = excl;
        cur[t] = excl;
        dlt[t] = atomicAdd(&gcur[t], v);
    }
    __syncthreads();

    #pragma unroll
    for (int k = 0; k < 16; ++k) {
        if (bk[k] >= 0) {
            const int p = atomicAdd(&cur[bk[k]], 1);
            recs[p] = pk[k];
        }
    }
    __syncthreads();

    const int w    = t >> 6;
    const int lane = t & 63;
    for (int b = w; b < NB; b += 16) {
        const int n = cnt[b];
        const int o = pos[b];
        const int g = dlt[b];
        for (int i = lane; i < n; i += 64)
            packed[g + i] = recs[o + i];
    }
}

// ===========================================================================
// 4) Per-bucket CSR sort (in place via LDS staging)
// ===========================================================================
__global__ __launch_bounds__(512) void k_sortb(
    const int* __restrict__ off, const int* __restrict__ cntg,
    int* packed,
    int* __restrict__ node_off, int* __restrict__ node_cnt)
{
    __shared__ int recs[CAP];
    __shared__ int lcnt[256];
    __shared__ int sc[256];
    __shared__ int lcur[NPB];

    const int t      = threadIdx.x;
    const int bucket = blockIdx.x;
    const int base   = off[bucket];
    int total = cntg[bucket];
    if (total > CAP) total = CAP;

    if (t < 256) lcnt[t] = 0;
    __syncthreads();

    for (int i = t; i < total; i += 512) {
        const int r = packed[base + i];
        recs[i] = r;
        atomicAdd(&lcnt[r >> 17], 1);
    }
    __syncthreads();

    if (t < 256) sc[t] = lcnt[t];
    __syncthreads();
    for (int o = 1; o < 256; o <<= 1) {
        int x = 0;
        if (t < 256 && t >= o) x = sc[t - o];
        __syncthreads();
        if (t < 256) sc[t] += x;
        __syncthreads();
    }

    if (t < NPB) {
        const int excl = sc[t] - lcnt[t];
        lcur[t] = excl;
        const int n = bucket * NPB + t;
        if (n < N_NODES) {
            node_off[n] = base + excl;
            node_cnt[n] = lcnt[t];
        }
    }
    __syncthreads();

    for (int i = t; i < total; i += 512) {
        const int r   = recs[i];
        const int pos = atomicAdd(&lcur[r >> 17], 1);
        packed[base + pos] = r & 0x1FFFF;
    }
}

// ===========================================================================
// 5a) F16 pull aggregation, one wave per node.  Packed v_pk_add_f16
//     accumulation (4 per 8 cols).  Writes the MEAN packed f16 into the
//     first 128B of out row n (row-private; update reads before overwrite).
// ===========================================================================
__global__ __launch_bounds__(256) void k_agg_f16(
    const unsigned int* __restrict__ ff16,
    const int* __restrict__ node_off,
    const int* __restrict__ node_cnt,
    const int* __restrict__ packed,
    float* __restrict__ out)
{
    const int gtid = blockIdx.x * 256 + threadIdx.x;
    const int n    = gtid >> 6;
    const int lane = gtid & 63;
    if (n >= N_NODES) return;

    const int start = node_off[n];
    const int deg   = node_cnt[n];
    const int sub   = lane >> 3;
    const int chunk = lane & 7;

    __half2 a0 = __floats2half2_rn(0.f, 0.f);
    __half2 a1 = a0, a2 = a0, a3 = a0;

    for (int b = 0; b < deg; b += 64) {
        const int rem = deg - b;
        const int p   = packed[start + b + ((lane < rem) ? lane : 0)];
        const int m   = (rem < 64) ? rem : 64;
        for (int g = 0; g < m; g += 8) {
            const int e = g + sub;
            const int s = __shfl(p, (e < m) ? e : 0);
            const uint4 v = ((const uint4*)ff16)[s * 8 + chunk];
            if (e < m) {
                a0 += bits2h(v.x);
                a1 += bits2h(v.y);
                a2 += bits2h(v.z);
                a3 += bits2h(v.w);
            }
        }
    }

    #pragma unroll
    for (int mask = 8; mask <= 32; mask <<= 1) {
        a0 += h2shfl_xor(a0, mask);
        a1 += h2shfl_xor(a1, mask);
        a2 += h2shfl_xor(a2, mask);
        a3 += h2shfl_xor(a3, mask);
    }

    if (lane < 8) {
        const float inv = 1.0f / (float)((deg > 0) ? deg : 1);
        uint4 mb;
        mb.x = h2bits(__floats2half2_rn(__low2float(a0) * inv, __high2float(a0) * inv));
        mb.y = h2bits(__floats2half2_rn(__low2float(a1) * inv, __high2float(a1) * inv));
        mb.z = h2bits(__floats2half2_rn(__low2float(a2) * inv, __high2float(a2) * inv));
        mb.w = h2bits(__floats2half2_rn(__low2float(a3) * inv, __high2float(a3) * inv));
        ((uint4*)out)[(size_t)n * 16 + lane] = mb;   // mean-f16, first 128B of row
    }
}

// ===========================================================================
// 6a) MFMA f16 dense update.  Block = 64 nodes, 4 waves x 16-node tile.
//     B frags from pre-converted w16 (no per-wave conversion).
//     A: row=lane&15, k=(lane>>4)*8+j;  C/D: col=lane&15, row=(lane>>4)*4+r.
// ===========================================================================
__global__ __launch_bounds__(256) void k_update_mfma(
    const unsigned int* __restrict__ ff16,
    const _Float16* __restrict__ w16,     // [2][64][64]: Ws then Wn, row c K-major
    float* out)
{
    const int wv   = threadIdx.x >> 6;
    const int lane = threadIdx.x & 63;
    const int n0   = blockIdx.x * 64 + wv * 16;
    const int r16  = lane & 15;
    const int g    = lane >> 4;

    half8 bws[4][2], bwn[4][2];
    #pragma unroll
    for (int nt = 0; nt < 4; ++nt) {
        const int c = nt * 16 + r16;
        #pragma unroll
        for (int kt = 0; kt < 2; ++kt) {
            const int k0 = kt * 32 + g * 8;
            bws[nt][kt] = *(const half8*)(w16 + c * 64 + k0);
            bwn[nt][kt] = *(const half8*)(w16 + 4096 + c * 64 + k0);
        }
    }

    const int arow = n0 + r16;
    const int rc   = (arow < N_NODES) ? arow : (N_NODES - 1);

    f32x4 acc[4] = {{0.f,0.f,0.f,0.f}, {0.f,0.f,0.f,0.f},
                    {0.f,0.f,0.f,0.f}, {0.f,0.f,0.f,0.f}};

    #pragma unroll
    for (int kt = 0; kt < 2; ++kt) {
        const int k8 = kt * 4 + g;
        const uint4 af_u = ((const uint4*)ff16)[(size_t)rc * 8 + k8];
        const uint4 am_u = ((const uint4*)out )[(size_t)rc * 16 + k8];
        const half8 af = *(const half8*)&af_u;
        const half8 am = *(const half8*)&am_u;
        #pragma unroll
        for (int nt = 0; nt < 4; ++nt) {
            acc[nt] = __builtin_amdgcn_mfma_f32_16x16x32_f16(af, bws[nt][kt], acc[nt], 0, 0, 0);
            acc[nt] = __builtin_amdgcn_mfma_f32_16x16x32_f16(am, bwn[nt][kt], acc[nt], 0, 0, 0);
        }
    }

    #pragma unroll
    for (int nt = 0; nt < 4; ++nt) {
        #pragma unroll
        for (int r = 0; r < 4; ++r) {
            const int ro = n0 + g * 4 + r;
            if (ro < N_NODES)
                out[(size_t)ro * 64 + nt * 16 + r16] = acc[nt][r];
        }
    }
}

// ===========================================================================
// tier-1 fp32 fallbacks (R7 structure)
// ===========================================================================
__global__ __launch_bounds__(256) void k_hist1(
    const int* __restrict__ dst, int* __restrict__ cnt)
{
    __shared__ int h[NB];
    const int t = threadIdx.x;
    for (int i = t; i < NB; i += 256) h[i] = 0;
    __syncthreads();
    for (int e = blockIdx.x * 256 + t; e < N_EDGES; e += gridDim.x * 256)
        atomicAdd(&h[dst[e] / NPB], 1);
    __syncthreads();
    for (int i = t; i < NB; i += 256)
        if (h[i]) atomicAdd(&cnt[i], h[i]);
}

__global__ __launch_bounds__(256) void k_aggregate(
    const float* __restrict__ feat,
    const int*   __restrict__ node_off,
    const int*   __restrict__ node_cnt,
    const int*   __restrict__ packed,
    float*       __restrict__ out)
{
    const int gtid = blockIdx.x * 256 + threadIdx.x;
    const int n    = gtid >> 6;
    const int lane = gtid & 63;
    if (n >= N_NODES) return;

    const int start = node_off[n];
    const int deg   = node_cnt[n];

    float a0 = 0.f, a1 = 0.f, a2 = 0.f, a3 = 0.f;
    for (int b = 0; b < deg; b += 64) {
        const int rem = deg - b;
        const int p   = packed[start + b + ((lane < rem) ? lane : 0)];
        const int m   = (rem < 64) ? rem : 64;
        int i = 0;
        for (; i + 4 <= m; i += 4) {
            a0 += feat[__shfl(p, i)     * D + lane];
            a1 += feat[__shfl(p, i + 1) * D + lane];
            a2 += feat[__shfl(p, i + 2) * D + lane];
            a3 += feat[__shfl(p, i + 3) * D + lane];
        }
        for (; i < m; ++i)
            a0 += feat[__shfl(p, i) * D + lane];
    }

    const float inv = 1.0f / (float)((deg > 0) ? deg : 1);
    out[n * D + lane] = ((a0 + a1) + (a2 + a3)) * inv;
}

#define RL(v, l) __int_as_float(__builtin_amdgcn_readlane(__float_as_int(v), (l)))

__global__ __launch_bounds__(256) void k_update(
    const float* __restrict__ feat,
    const float* __restrict__ Ws,
    const float* __restrict__ Wn,
    float* out)
{
    const int wid   = (blockIdx.x * 256 + threadIdx.x) >> 6;
    const int lane  = threadIdx.x & 63;
    const int nwave = (gridDim.x * 256) >> 6;

    const float4* Ws4 = (const float4*)Ws;
    const float4* Wn4 = (const float4*)Wn;
    float4 ws[16], wn[16];
    #pragma unroll
    for (int j = 0; j < 16; ++j) {
        ws[j] = Ws4[lane * 16 + j];
        wn[j] = Wn4[lane * 16 + j];
    }

    for (int n = wid; n < N_NODES; n += nwave) {
        const float f = feat[n * D + lane];
        const float a = out[n * D + lane];
        float s0 = 0.f, s1 = 0.f, m0 = 0.f, m1 = 0.f;
        #pragma unroll
        for (int j = 0; j < 16; ++j) {
            const float4 w_s = ws[j];
            const float4 w_n = wn[j];
            s0 = fmaf(RL(f, 4 * j + 0), w_s.x, s0);
            s1 = fmaf(RL(f, 4 * j + 1), w_s.y, s1);
            s0 = fmaf(RL(f, 4 * j + 2), w_s.z, s0);
            s1 = fmaf(RL(f, 4 * j + 3), w_s.w, s1);
            m0 = fmaf(RL(a, 4 * j + 0), w_n.x, m0);
            m1 = fmaf(RL(a, 4 * j + 1), w_n.y, m1);
            m0 = fmaf(RL(a, 4 * j + 2), w_n.z, m0);
            m1 = fmaf(RL(a, 4 * j + 3), w_n.w, m1);
        }
        out[n * D + lane] = (s0 + s1) + (m0 + m1);
    }
}

// ===========================================================================
// tier-0 fallback (tiny ws)
// ===========================================================================
__global__ __launch_bounds__(256) void sage_scatter(
    const float* __restrict__ feat,
    const int*   __restrict__ src,
    const int*   __restrict__ dst,
    float*       __restrict__ agg,
    float*       __restrict__ deg)
{
    const int gtid = blockIdx.x * blockDim.x + threadIdx.x;
    const int edge = gtid >> 6;
    const int lane = gtid & 63;
    if (edge >= N_EDGES) return;
    const int s = src[edge];
    const int d = dst[edge];
    atomicAdd(&agg[d * D + lane], feat[s * D + lane]);
    if (lane == 0) atomicAdd(&deg[d], 1.0f);
}

__global__ __launch_bounds__(256) void k_update_div(
    const float* __restrict__ feat,
    const float* __restrict__ Ws,
    const float* __restrict__ Wn,
    const float* __restrict__ deg,
    float* out)
{
    const int wid   = (blockIdx.x * 256 + threadIdx.x) >> 6;
    const int lane  = threadIdx.x & 63;
    const int nwave = (gridDim.x * 256) >> 6;

    const float4* Ws4 = (const float4*)Ws;
    const float4* Wn4 = (const float4*)Wn;
    float4 ws[16], wn[16];
    #pragma unroll
    for (int j = 0; j < 16; ++j) {
        ws[j] = Ws4[lane * 16 + j];
        wn[j] = Wn4[lane * 16 + j];
    }

    for (int n = wid; n < N_NODES; n += nwave) {
        const float f = feat[n * D + lane];
        const float a = out[n * D + lane] / fmaxf(deg[n], 1.0f);
        float s0 = 0.f, s1 = 0.f, m0 = 0.f, m1 = 0.f;
        #pragma unroll
        for (int j = 0; j < 16; ++j) {
            const float4 w_s = ws[j];
            const float4 w_n = wn[j];
            s0 = fmaf(RL(f, 4 * j + 0), w_s.x, s0);
            s1 = fmaf(RL(f, 4 * j + 1), w_s.y, s1);
            s0 = fmaf(RL(f, 4 * j + 2), w_s.z, s0);
            s1 = fmaf(RL(f, 4 * j + 3), w_s.w, s1);
            m0 = fmaf(RL(a, 4 * j + 0), w_n.x, m0);
            m1 = fmaf(RL(a, 4 * j + 1), w_n.y, m1);
            m0 = fmaf(RL(a, 4 * j + 2), w_n.z, m0);
            m1 = fmaf(RL(a, 4 * j + 3), w_n.w, m1);
        }
        out[n * D + lane] = (s0 + s1) + (m0 + m1);
    }
}

extern "C" void kernel_launch(void* const* d_in, const int* in_sizes, int n_in,
                              void* d_out, int out_size, void* d_ws, size_t ws_size,
                              hipStream_t stream) {
    const float* feat = (const float*)d_in[0];
    const int*   src  = (const int*)d_in[1];
    const int*   dst  = (const int*)d_in[2];
    const float* Ws   = (const float*)d_in[3];
    const float* Wn   = (const float*)d_in[4];
    float* out = (float*)d_out;
    char*  ws  = (char*)d_ws;

    if (ws_size >= W2_NEED) {
        unsigned int* ff16 = (unsigned int*)(ws + W2_FF16);
        int* packed = (int*)(ws + W2_PACKED);
        int* cnt    = (int*)(ws + W2_CNT);
        int* off    = (int*)(ws + W2_OFF);
        int* gcur   = (int*)(ws + W2_GCUR);
        int* noff   = (int*)(ws + W2_NODEOFF);
        int* ncnt   = (int*)(ws + W2_NODECNT);
        unsigned int* w16u = (unsigned int*)(ws + W2_W16);

        hipMemsetAsync(cnt, 0, (size_t)NB * sizeof(int), stream);

        k_prep       <<<1281, 256,  0, stream>>>(feat, dst, Ws, Wn, ff16, cnt, w16u);
        k_scan       <<<1,    512,  0, stream>>>(cnt, off, gcur);
        k_partition  <<<PBLK, 1024, 0, stream>>>(src, dst, gcur, packed);
        k_sortb      <<<NB,   512,  0, stream>>>(off, cnt, packed, noff, ncnt);
        k_agg_f16    <<<(N_NODES * 64 + 255) / 256, 256, 0, stream>>>(
            ff16, noff, ncnt, packed, out);
        k_update_mfma<<<(N_NODES + 63) / 64, 256, 0, stream>>>(
            ff16, (const _Float16*)w16u, out);
    } else if (ws_size >= W1_NEED) {
        int* packed = (int*)(ws + W1_PACKED);
        int* cnt    = (int*)(ws + W1_CNT);
        int* off    = (int*)(ws + W1_OFF);
        int* gcur   = (int*)(ws + W1_GCUR);
        int* noff   = (int*)(ws + W1_NODEOFF);
        int* ncnt   = (int*)(ws + W1_NODECNT);

        hipMemsetAsync(cnt, 0, (size_t)NB * sizeof(int), stream);

        k_hist1    <<<256,  256,  0, stream>>>(dst, cnt);
        k_scan     <<<1,    512,  0, stream>>>(cnt, off, gcur);
        k_partition<<<PBLK, 1024, 0, stream>>>(src, dst, gcur, packed);
        k_sortb    <<<NB,   512,  0, stream>>>(off, cnt, packed, noff, ncnt);
        k_aggregate<<<(N_NODES * 64 + 255) / 256, 256, 0, stream>>>(
            feat, noff, ncnt, packed, out);
        k_update   <<<1024, 256,  0, stream>>>(feat, Ws, Wn, out);
    } else {
        float* deg = (float*)ws;
        hipMemsetAsync(out, 0, (size_t)N_NODES * D * sizeof(float), stream);
        hipMemsetAsync(deg, 0, (size_t)N_NODES * sizeof(float), stream);
        sage_scatter<<<(N_EDGES * 64) / 256, 256, 0, stream>>>(feat, src, dst, out, deg);
        k_update_div<<<1024, 256, 0, stream>>>(feat, Ws, Wn, deg, out);
    }
}

// Round 11
// 114.856 us; speedup vs baseline: 7.8247x; 1.0454x over previous
//
#include <hip/hip_runtime.h>
#include <hip/hip_fp16.h>

#define N_NODES 100000
#define N_EDGES 1600000
#define D 64
#define ZROW 100000                        // zero-row sentinel index in ff16

// ---- bucket geometry ----
#define NPB   240
#define NB    417
#define CAP   8192

// ---- partition geometry ----
#define EPB   8192
#define PBLK  ((N_EDGES + EPB - 1) / EPB)  // 196

// ---- ws layout tier 2 (f16 gather + MFMA update), ~20.02 MB ----
#define W2_FF16     0u                           // f16[(N_NODES+1)*D] 12.80 MB
#define W2_PACKED   12800128u                    // int[N_EDGES] 6.4 MB
#define W2_CNT      (W2_PACKED + 4u * N_EDGES)
#define W2_OFF      (W2_CNT  + 4u * NB)
#define W2_GCUR     (W2_OFF  + 4u * NB)
#define W2_NODEOFF  (W2_GCUR + 4u * NB)
#define W2_NODECNT  (W2_NODEOFF + 4u * N_NODES)
#define W2_W16      (W2_NODECNT + 4u * N_NODES)  // f16[2*64*64] = 16 KB
#define W2_NEED     (W2_W16 + 16384u)

// ---- ws layout tier 1 (fp32, R7) ----
#define W1_PACKED   0u
#define W1_CNT      (4u * N_EDGES)
#define W1_OFF      (W1_CNT  + 4u * NB)
#define W1_GCUR     (W1_OFF  + 4u * NB)
#define W1_NODEOFF  (W1_GCUR + 4u * NB)
#define W1_NODECNT  (W1_NODEOFF + 4u * N_NODES)
#define W1_NEED     (W1_NODECNT + 4u * N_NODES)

typedef __attribute__((ext_vector_type(8))) _Float16 half8;
typedef __attribute__((ext_vector_type(4))) float f32x4;

__device__ inline unsigned int h2bits(__half2 h) { return *(unsigned int*)&h; }
__device__ inline __half2 bits2h(unsigned int u) { return *(__half2*)&u; }
__device__ inline __half2 h2shfl_xor(__half2 x, int mask) {
    int i = *(int*)&x;
    i = __shfl_xor(i, mask);
    return *(__half2*)&i;
}

// ===========================================================================
// 0) Fused prep: blocks [0,1024) feat->f16; [1024,1280) dst histogram;
//    block 1280: W->f16 + zero-row init.
// ===========================================================================
__global__ __launch_bounds__(256) void k_prep(
    const float* __restrict__ feat, const int* __restrict__ dst,
    const float* __restrict__ Ws, const float* __restrict__ Wn,
    unsigned int* __restrict__ ff16, int* __restrict__ cnt,
    unsigned int* __restrict__ w16)
{
    __shared__ int h[NB];
    const int bid = blockIdx.x;
    const int t   = threadIdx.x;

    if (bid < 1024) {
        const int total = N_NODES * D / 8;     // 800000 uint4 outputs
        for (int i = bid * 256 + t; i < total; i += 1024 * 256) {
            const float4 x = ((const float4*)feat)[i * 2];
            const float4 y = ((const float4*)feat)[i * 2 + 1];
            uint4 o;
            o.x = h2bits(__floats2half2_rn(x.x, x.y));
            o.y = h2bits(__floats2half2_rn(x.z, x.w));
            o.z = h2bits(__floats2half2_rn(y.x, y.y));
            o.w = h2bits(__floats2half2_rn(y.z, y.w));
            ((uint4*)ff16)[i] = o;
        }
    } else if (bid < 1280) {
        for (int i = t; i < NB; i += 256) h[i] = 0;
        __syncthreads();
        for (int e = (bid - 1024) * 256 + t; e < N_EDGES; e += 256 * 256)
            atomicAdd(&h[dst[e] / NPB], 1);
        __syncthreads();
        for (int i = t; i < NB; i += 256)
            if (h[i]) atomicAdd(&cnt[i], h[i]);
    } else {
        for (int i = t; i < 2048; i += 256)
            w16[i] = h2bits(__floats2half2_rn(Ws[2 * i], Ws[2 * i + 1]));
        for (int i = t; i < 2048; i += 256)
            w16[2048 + i] = h2bits(__floats2half2_rn(Wn[2 * i], Wn[2 * i + 1]));
        if (t < 32) ff16[ZROW * 32 + t] = 0;    // zero sentinel row
    }
}

// ===========================================================================
// 2) Exclusive scan of cnt[NB] -> off; seed global cursors
// ===========================================================================
__global__ __launch_bounds__(512) void k_scan(
    const int* __restrict__ cnt, int* __restrict__ off, int* __restrict__ gcur)
{
    __shared__ int lds[512];
    const int t = threadIdx.x;
    const int v = (t < NB) ? cnt[t] : 0;
    lds[t] = v;
    __syncthreads();
    for (int o = 1; o < 512; o <<= 1) {
        const int x = (t >= o) ? lds[t - o] : 0;
        __syncthreads();
        lds[t] += x;
        __syncthreads();
    }
    if (t < NB) {
        const int excl = lds[t] - v;
        off[t]  = excl;
        gcur[t] = excl;
    }
}

// ===========================================================================
// 3) Block-chunked partition: EPB=8192, 1024 thr, 8 edges/thread,
//    196 blocks (~2 blocks/CU with 42KB LDS).
// ===========================================================================
__global__ __launch_bounds__(1024) void k_partition(
    const int* __restrict__ src, const int* __restrict__ dst,
    int* __restrict__ gcur, int* __restrict__ packed)
{
    __shared__ int recs[EPB];        // 32 KB
    __shared__ int cnt[NB];
    __shared__ int scn[512];
    __shared__ int pos[NB];
    __shared__ int cur[NB];
    __shared__ int dlt[NB];

    const int t  = threadIdx.x;
    const int e0 = blockIdx.x * EPB;
    const int nE = min(EPB, N_EDGES - e0);

    for (int i = t; i < NB; i += 1024) cnt[i] = 0;
    __syncthreads();

    int pk[8], bk[8];
    #pragma unroll
    for (int k = 0; k < 8; ++k) {
        const int i = t + k * 1024;
        if (i < nE) {
            const int d  = dst[e0 + i];
            const int b  = d / NPB;
            const int dl = d - b * NPB;
            pk[k] = src[e0 + i] | (dl << 17);
            bk[k] = b;
            atomicAdd(&cnt[b], 1);
        } else {
            bk[k] = -1;
        }
    }
    __syncthreads();

    if (t < 512) scn[t] = (t < NB) ? cnt[t] : 0;
    __syncthreads();
    for (int o = 1; o < 512; o <<= 1) {
        int x = 0;
        if (t < 512 && t >= o) x = scn[t - o];
        __syncthreads();
        if (t < 512) scn[t] += x;
        __syncthreads();
    }
    if (t < NB) {
        const int v    = cnt[t];
        const int excl = scn[t] - v;
        pos[t] = excl;
        cur[t] = excl;
        dlt[t] = atomicAdd(&gcur[t], v);
    }
    __syncthreads();

    #pragma unroll
    for (int k = 0; k < 8; ++k) {
        if (bk[k] >= 0) {
            const int p = atomicAdd(&cur[bk[k]], 1);
            recs[p] = pk[k];
        }
    }
    __syncthreads();

    const int w    = t >> 6;
    const int lane = t & 63;
    for (int b = w; b < NB; b += 16) {
        const int n = cnt[b];
        const int o = pos[b];
        const int g = dlt[b];
        for (int i = lane; i < n; i += 64)
            packed[g + i] = recs[o + i];
    }
}

// ===========================================================================
// 4) Per-bucket CSR sort (in place via LDS staging)
// ===========================================================================
__global__ __launch_bounds__(512) void k_sortb(
    const int* __restrict__ off, const int* __restrict__ cntg,
    int* packed,
    int* __restrict__ node_off, int* __restrict__ node_cnt)
{
    __shared__ int recs[CAP];
    __shared__ int lcnt[256];
    __shared__ int sc[256];
    __shared__ int lcur[NPB];

    const int t      = threadIdx.x;
    const int bucket = blockIdx.x;
    const int base   = off[bucket];
    int total = cntg[bucket];
    if (total > CAP) total = CAP;

    if (t < 256) lcnt[t] = 0;
    __syncthreads();

    for (int i = t; i < total; i += 512) {
        const int r = packed[base + i];
        recs[i] = r;
        atomicAdd(&lcnt[r >> 17], 1);
    }
    __syncthreads();

    if (t < 256) sc[t] = lcnt[t];
    __syncthreads();
    for (int o = 1; o < 256; o <<= 1) {
        int x = 0;
        if (t < 256 && t >= o) x = sc[t - o];
        __syncthreads();
        if (t < 256) sc[t] += x;
        __syncthreads();
    }

    if (t < NPB) {
        const int excl = sc[t] - lcnt[t];
        lcur[t] = excl;
        const int n = bucket * NPB + t;
        if (n < N_NODES) {
            node_off[n] = base + excl;
            node_cnt[n] = lcnt[t];
        }
    }
    __syncthreads();

    for (int i = t; i < total; i += 512) {
        const int r   = recs[i];
        const int pos = atomicAdd(&lcur[r >> 17], 1);
        packed[base + pos] = r & 0x1FFFF;
    }
}

// ===========================================================================
// 5a) F16 pull aggregation, one wave per node.  Zero-row sentinel makes the
//     inner loop branch-free; 2x group unroll doubles loads in flight.
//     Writes the MEAN packed f16 into the first 128B of out row n.
// ===========================================================================
__global__ __launch_bounds__(256) void k_agg_f16(
    const unsigned int* __restrict__ ff16,
    const int* __restrict__ node_off,
    const int* __restrict__ node_cnt,
    const int* __restrict__ packed,
    float* __restrict__ out)
{
    const int gtid = blockIdx.x * 256 + threadIdx.x;
    const int n    = gtid >> 6;
    const int lane = gtid & 63;
    if (n >= N_NODES) return;

    const int start = node_off[n];
    const int deg   = node_cnt[n];
    const int sub   = lane >> 3;       // edge slot (0..7)
    const int chunk = lane & 7;        // 16B chunk of the 128B row

    __half2 a0 = __floats2half2_rn(0.f, 0.f);
    __half2 a1 = a0, a2 = a0, a3 = a0;

    for (int b = 0; b < deg; b += 64) {
        const int rem = min(deg - b, 64);
        int p = ZROW;
        if (lane < rem) p = packed[start + b + lane];

        const int npair = (rem + 15) >> 4;          // 16-edge pairs
        for (int q = 0; q < npair; ++q) {
            const int e0 = q * 16 + sub;            // < 64 always
            const int s0 = __shfl(p, e0)     & 0x1FFFF;
            const int s1 = __shfl(p, e0 + 8) & 0x1FFFF;
            const uint4 v0 = ((const uint4*)ff16)[(size_t)s0 * 8 + chunk];
            const uint4 v1 = ((const uint4*)ff16)[(size_t)s1 * 8 + chunk];
            a0 += bits2h(v0.x);
            a1 += bits2h(v0.y);
            a2 += bits2h(v0.z);
            a3 += bits2h(v0.w);
            a0 += bits2h(v1.x);
            a1 += bits2h(v1.y);
            a2 += bits2h(v1.z);
            a3 += bits2h(v1.w);
        }
    }

    #pragma unroll
    for (int mask = 8; mask <= 32; mask <<= 1) {
        a0 += h2shfl_xor(a0, mask);
        a1 += h2shfl_xor(a1, mask);
        a2 += h2shfl_xor(a2, mask);
        a3 += h2shfl_xor(a3, mask);
    }

    if (lane < 8) {
        const float inv = 1.0f / (float)((deg > 0) ? deg : 1);
        uint4 mb;
        mb.x = h2bits(__floats2half2_rn(__low2float(a0) * inv, __high2float(a0) * inv));
        mb.y = h2bits(__floats2half2_rn(__low2float(a1) * inv, __high2float(a1) * inv));
        mb.z = h2bits(__floats2half2_rn(__low2float(a2) * inv, __high2float(a2) * inv));
        mb.w = h2bits(__floats2half2_rn(__low2float(a3) * inv, __high2float(a3) * inv));
        ((uint4*)out)[(size_t)n * 16 + lane] = mb;   // mean-f16, first 128B of row
    }
}

// ===========================================================================
// 6a) MFMA f16 dense update (R10).  Block = 64 nodes, 4 waves x 16-node tile.
// ===========================================================================
__global__ __launch_bounds__(256) void k_update_mfma(
    const unsigned int* __restrict__ ff16,
    const _Float16* __restrict__ w16,     // [2][64][64]: Ws then Wn, K-major
    float* out)
{
    const int wv   = threadIdx.x >> 6;
    const int lane = threadIdx.x & 63;
    const int n0   = blockIdx.x * 64 + wv * 16;
    const int r16  = lane & 15;
    const int g    = lane >> 4;

    half8 bws[4][2], bwn[4][2];
    #pragma unroll
    for (int nt = 0; nt < 4; ++nt) {
        const int c = nt * 16 + r16;
        #pragma unroll
        for (int kt = 0; kt < 2; ++kt) {
            const int k0 = kt * 32 + g * 8;
            bws[nt][kt] = *(const half8*)(w16 + c * 64 + k0);
            bwn[nt][kt] = *(const half8*)(w16 + 4096 + c * 64 + k0);
        }
    }

    const int arow = n0 + r16;
    const int rc   = (arow < N_NODES) ? arow : (N_NODES - 1);

    f32x4 acc[4] = {{0.f,0.f,0.f,0.f}, {0.f,0.f,0.f,0.f},
                    {0.f,0.f,0.f,0.f}, {0.f,0.f,0.f,0.f}};

    #pragma unroll
    for (int kt = 0; kt < 2; ++kt) {
        const int k8 = kt * 4 + g;
        const uint4 af_u = ((const uint4*)ff16)[(size_t)rc * 8 + k8];
        const uint4 am_u = ((const uint4*)out )[(size_t)rc * 16 + k8];
        const half8 af = *(const half8*)&af_u;
        const half8 am = *(const half8*)&am_u;
        #pragma unroll
        for (int nt = 0; nt < 4; ++nt) {
            acc[nt] = __builtin_amdgcn_mfma_f32_16x16x32_f16(af, bws[nt][kt], acc[nt], 0, 0, 0);
            acc[nt] = __builtin_amdgcn_mfma_f32_16x16x32_f16(am, bwn[nt][kt], acc[nt], 0, 0, 0);
        }
    }

    #pragma unroll
    for (int nt = 0; nt < 4; ++nt) {
        #pragma unroll
        for (int r = 0; r < 4; ++r) {
            const int ro = n0 + g * 4 + r;
            if (ro < N_NODES)
                out[(size_t)ro * 64 + nt * 16 + r16] = acc[nt][r];
        }
    }
}

// ===========================================================================
// tier-1 fp32 fallbacks (R7 structure)
// ===========================================================================
__global__ __launch_bounds__(256) void k_hist1(
    const int* __restrict__ dst, int* __restrict__ cnt)
{
    __shared__ int h[NB];
    const int t = threadIdx.x;
    for (int i = t; i < NB; i += 256) h[i] = 0;
    __syncthreads();
    for (int e = blockIdx.x * 256 + t; e < N_EDGES; e += gridDim.x * 256)
        atomicAdd(&h[dst[e] / NPB], 1);
    __syncthreads();
    for (int i = t; i < NB; i += 256)
        if (h[i]) atomicAdd(&cnt[i], h[i]);
}

__global__ __launch_bounds__(256) void k_aggregate(
    const float* __restrict__ feat,
    const int*   __restrict__ node_off,
    const int*   __restrict__ node_cnt,
    const int*   __restrict__ packed,
    float*       __restrict__ out)
{
    const int gtid = blockIdx.x * 256 + threadIdx.x;
    const int n    = gtid >> 6;
    const int lane = gtid & 63;
    if (n >= N_NODES) return;

    const int start = node_off[n];
    const int deg   = node_cnt[n];

    float a0 = 0.f, a1 = 0.f, a2 = 0.f, a3 = 0.f;
    for (int b = 0; b < deg; b += 64) {
        const int rem = deg - b;
        const int p   = packed[start + b + ((lane < rem) ? lane : 0)];
        const int m   = (rem < 64) ? rem : 64;
        int i = 0;
        for (; i + 4 <= m; i += 4) {
            a0 += feat[__shfl(p, i)     * D + lane];
            a1 += feat[__shfl(p, i + 1) * D + lane];
            a2 += feat[__shfl(p, i + 2) * D + lane];
            a3 += feat[__shfl(p, i + 3) * D + lane];
        }
        for (; i < m; ++i)
            a0 += feat[__shfl(p, i) * D + lane];
    }

    const float inv = 1.0f / (float)((deg > 0) ? deg : 1);
    out[n * D + lane] = ((a0 + a1) + (a2 + a3)) * inv;
}

#define RL(v, l) __int_as_float(__builtin_amdgcn_readlane(__float_as_int(v), (l)))

__global__ __launch_bounds__(256) void k_update(
    const float* __restrict__ feat,
    const float* __restrict__ Ws,
    const float* __restrict__ Wn,
    float* out)
{
    const int wid   = (blockIdx.x * 256 + threadIdx.x) >> 6;
    const int lane  = threadIdx.x & 63;
    const int nwave = (gridDim.x * 256) >> 6;

    const float4* Ws4 = (const float4*)Ws;
    const float4* Wn4 = (const float4*)Wn;
    float4 ws[16], wn[16];
    #pragma unroll
    for (int j = 0; j < 16; ++j) {
        ws[j] = Ws4[lane * 16 + j];
        wn[j] = Wn4[lane * 16 + j];
    }

    for (int n = wid; n < N_NODES; n += nwave) {
        const float f = feat[n * D + lane];
        const float a = out[n * D + lane];
        float s0 = 0.f, s1 = 0.f, m0 = 0.f, m1 = 0.f;
        #pragma unroll
        for (int j = 0; j < 16; ++j) {
            const float4 w_s = ws[j];
            const float4 w_n = wn[j];
            s0 = fmaf(RL(f, 4 * j + 0), w_s.x, s0);
            s1 = fmaf(RL(f, 4 * j + 1), w_s.y, s1);
            s0 = fmaf(RL(f, 4 * j + 2), w_s.z, s0);
            s1 = fmaf(RL(f, 4 * j + 3), w_s.w, s1);
            m0 = fmaf(RL(a, 4 * j + 0), w_n.x, m0);
            m1 = fmaf(RL(a, 4 * j + 1), w_n.y, m1);
            m0 = fmaf(RL(a, 4 * j + 2), w_n.z, m0);
            m1 = fmaf(RL(a, 4 * j + 3), w_n.w, m1);
        }
        out[n * D + lane] = (s0 + s1) + (m0 + m1);
    }
}

// ===========================================================================
// tier-0 fallback (tiny ws)
// ===========================================================================
__global__ __launch_bounds__(256) void sage_scatter(
    const float* __restrict__ feat,
    const int*   __restrict__ src,
    const int*   __restrict__ dst,
    float*       __restrict__ agg,
    float*       __restrict__ deg)
{
    const int gtid = blockIdx.x * blockDim.x + threadIdx.x;
    const int edge = gtid >> 6;
    const int lane = gtid & 63;
    if (edge >= N_EDGES) return;
    const int s = src[edge];
    const int d = dst[edge];
    atomicAdd(&agg[d * D + lane], feat[s * D + lane]);
    if (lane == 0) atomicAdd(&deg[d], 1.0f);
}

__global__ __launch_bounds__(256) void k_update_div(
    const float* __restrict__ feat,
    const float* __restrict__ Ws,
    const float* __restrict__ Wn,
    const float* __restrict__ deg,
    float* out)
{
    const int wid   = (blockIdx.x * 256 + threadIdx.x) >> 6;
    const int lane  = threadIdx.x & 63;
    const int nwave = (gridDim.x * 256) >> 6;

    const float4* Ws4 = (const float4*)Ws;
    const float4* Wn4 = (const float4*)Wn;
    float4 ws[16], wn[16];
    #pragma unroll
    for (int j = 0; j < 16; ++j) {
        ws[j] = Ws4[lane * 16 + j];
        wn[j] = Wn4[lane * 16 + j];
    }

    for (int n = wid; n < N_NODES; n += nwave) {
        const float f = feat[n * D + lane];
        const float a = out[n * D + lane] / fmaxf(deg[n], 1.0f);
        float s0 = 0.f, s1 = 0.f, m0 = 0.f, m1 = 0.f;
        #pragma unroll
        for (int j = 0; j < 16; ++j) {
            const float4 w_s = ws[j];
            const float4 w_n = wn[j];
            s0 = fmaf(RL(f, 4 * j + 0), w_s.x, s0);
            s1 = fmaf(RL(f, 4 * j + 1), w_s.y, s1);
            s0 = fmaf(RL(f, 4 * j + 2), w_s.z, s0);
            s1 = fmaf(RL(f, 4 * j + 3), w_s.w, s1);
            m0 = fmaf(RL(a, 4 * j + 0), w_n.x, m0);
            m1 = fmaf(RL(a, 4 * j + 1), w_n.y, m1);
            m0 = fmaf(RL(a, 4 * j + 2), w_n.z, m0);
            m1 = fmaf(RL(a, 4 * j + 3), w_n.w, m1);
        }
        out[n * D + lane] = (s0 + s1) + (m0 + m1);
    }
}

extern "C" void kernel_launch(void* const* d_in, const int* in_sizes, int n_in,
                              void* d_out, int out_size, void* d_ws, size_t ws_size,
                              hipStream_t stream) {
    const float* feat = (const float*)d_in[0];
    const int*   src  = (const int*)d_in[1];
    const int*   dst  = (const int*)d_in[2];
    const float* Ws   = (const float*)d_in[3];
    const float* Wn   = (const float*)d_in[4];
    float* out = (float*)d_out;
    char*  ws  = (char*)d_ws;

    if (ws_size >= W2_NEED) {
        unsigned int* ff16 = (unsigned int*)(ws + W2_FF16);
        int* packed = (int*)(ws + W2_PACKED);
        int* cnt    = (int*)(ws + W2_CNT);
        int* off    = (int*)(ws + W2_OFF);
        int* gcur   = (int*)(ws + W2_GCUR);
        int* noff   = (int*)(ws + W2_NODEOFF);
        int* ncnt   = (int*)(ws + W2_NODECNT);
        unsigned int* w16u = (unsigned int*)(ws + W2_W16);

        hipMemsetAsync(cnt, 0, (size_t)NB * sizeof(int), stream);

        k_prep       <<<1281, 256,  0, stream>>>(feat, dst, Ws, Wn, ff16, cnt, w16u);
        k_scan       <<<1,    512,  0, stream>>>(cnt, off, gcur);
        k_partition  <<<PBLK, 1024, 0, stream>>>(src, dst, gcur, packed);
        k_sortb      <<<NB,   512,  0, stream>>>(off, cnt, packed, noff, ncnt);
        k_agg_f16    <<<(N_NODES * 64 + 255) / 256, 256, 0, stream>>>(
            ff16, noff, ncnt, packed, out);
        k_update_mfma<<<(N_NODES + 63) / 64, 256, 0, stream>>>(
            ff16, (const _Float16*)w16u, out);
    } else if (ws_size >= W1_NEED) {
        int* packed = (int*)(ws + W1_PACKED);
        int* cnt    = (int*)(ws + W1_CNT);
        int* off    = (int*)(ws + W1_OFF);
        int* gcur   = (int*)(ws + W1_GCUR);
        int* noff   = (int*)(ws + W1_NODEOFF);
        int* ncnt   = (int*)(ws + W1_NODECNT);

        hipMemsetAsync(cnt, 0, (size_t)NB * sizeof(int), stream);

        k_hist1    <<<256,  256,  0, stream>>>(dst, cnt);
        k_scan     <<<1,    512,  0, stream>>>(cnt, off, gcur);
        k_partition<<<PBLK, 1024, 0, stream>>>(src, dst, gcur, packed);
        k_sortb    <<<NB,   512,  0, stream>>>(off, cnt, packed, noff, ncnt);
        k_aggregate<<<(N_NODES * 64 + 255) / 256, 256, 0, stream>>>(
            feat, noff, ncnt, packed, out);
        k_update   <<<1024, 256,  0, stream>>>(feat, Ws, Wn, out);
    } else {
        float* deg = (float*)ws;
        hipMemsetAsync(out, 0, (size_t)N_NODES * D * sizeof(float), stream);
        hipMemsetAsync(deg, 0, (size_t)N_NODES * sizeof(float), stream);
        sage_scatter<<<(N_EDGES * 64) / 256, 256, 0, stream>>>(feat, src, dst, out, deg);
        k_update_div<<<1024, 256, 0, stream>>>(feat, Ws, Wn, deg, out);
    }
}

// Round 13
// 98.020 us; speedup vs baseline: 9.1687x; 1.1718x over previous
//
#include <hip/hip_runtime.h>
#include <hip/hip_fp16.h>

#define N_NODES 100000
#define N_EDGES 1600000
#define D 64
#define ZROW 100000                        // zero-row sentinel index in ff16

// ---- bucket geometry (fixed-capacity regions; no hist/scan needed) ----
#define NPB   240
#define NB    417
#define CAP   8192                         // per-bucket region (Poisson 3837+-62)

// ---- partition geometry ----
#define EPB   8192
#define PBLK  ((N_EDGES + EPB - 1) / EPB)  // 196
#define CONVB 256                          // feat-conversion blocks in k_part_conv

// ---- ws layout tier 3 (~27.3 MB; observed ws ~268 MB) ----
#define W3_FF16     0u                            // f16[(N_NODES+1)*D] 12.80 MB
#define W3_PACKED   12800128u                     // int[NB*CAP] 13.66 MB
#define W3_GCUR     (W3_PACKED + 4u * NB * CAP)   // int[NB]
#define W3_NODEOFF  (W3_GCUR + 4u * NB)           // int[N_NODES]
#define W3_NODECNT  (W3_NODEOFF + 4u * N_NODES)   // int[N_NODES]
#define W3_W16      (W3_NODECNT + 4u * N_NODES)   // f16[2*64*64] = 16 KB
#define W3_NEED     (W3_W16 + 16384u)             // 27,282,436 B

typedef __attribute__((ext_vector_type(8))) _Float16 half8;
typedef __attribute__((ext_vector_type(4))) float f32x4;

__device__ inline unsigned int h2bits(__half2 h) { return *(unsigned int*)&h; }
__device__ inline __half2 bits2h(unsigned int u) { return *(__half2*)&u; }
__device__ inline __half2 h2shfl_xor(__half2 x, int mask) {
    int i = *(int*)&x;
    i = __shfl_xor(i, mask);
    return *(__half2*)&i;
}

// ===========================================================================
// 1) Fused partition + conversions.  Blocks [0,PBLK): block-chunked counting
//    sort into fixed per-bucket regions.  Blocks [PBLK,PBLK+CONVB): feat->f16.
//    Block PBLK+CONVB: W->f16 (grid-stride over 2048, 1024 threads!) + zero row.
// ===========================================================================
__global__ __launch_bounds__(1024) void k_part_conv(
    const float* __restrict__ feat,
    const int* __restrict__ src, const int* __restrict__ dst,
    const float* __restrict__ Ws, const float* __restrict__ Wn,
    unsigned int* __restrict__ ff16, unsigned int* __restrict__ w16,
    int* __restrict__ gcur, int* __restrict__ packed)
{
    __shared__ int recs[EPB];        // 32 KB
    __shared__ int cnt[NB];
    __shared__ int scn[512];
    __shared__ int pos[NB];
    __shared__ int cur[NB];
    __shared__ int dlt[NB];

    const int bid = blockIdx.x;
    const int t   = threadIdx.x;

    if (bid >= PBLK) {
        if (bid < PBLK + CONVB) {
            // feat fp32 -> f16, 800000 uint4 outputs, grid-stride
            const int total = N_NODES * D / 8;
            for (int i = (bid - PBLK) * 1024 + t; i < total; i += CONVB * 1024) {
                const float4 x = ((const float4*)feat)[i * 2];
                const float4 y = ((const float4*)feat)[i * 2 + 1];
                uint4 o;
                o.x = h2bits(__floats2half2_rn(x.x, x.y));
                o.y = h2bits(__floats2half2_rn(x.z, x.w));
                o.z = h2bits(__floats2half2_rn(y.x, y.y));
                o.w = h2bits(__floats2half2_rn(y.z, y.w));
                ((uint4*)ff16)[i] = o;
            }
        } else {
            // FIX (R12 bug): 1024 threads must cover 2048 uints -> loop.
            for (int i = t; i < 2048; i += 1024) {
                w16[i]        = h2bits(__floats2half2_rn(Ws[2 * i], Ws[2 * i + 1]));
                w16[2048 + i] = h2bits(__floats2half2_rn(Wn[2 * i], Wn[2 * i + 1]));
            }
            if (t < 32) ff16[ZROW * 32 + t] = 0;    // zero sentinel row
        }
        return;
    }

    const int e0 = bid * EPB;
    const int nE = min(EPB, N_EDGES - e0);

    for (int i = t; i < NB; i += 1024) cnt[i] = 0;
    __syncthreads();

    int pk[8], bk[8];
    #pragma unroll
    for (int k = 0; k < 8; ++k) {
        const int i = t + k * 1024;
        if (i < nE) {
            const int d  = dst[e0 + i];
            const int b  = d / NPB;
            const int dl = d - b * NPB;
            pk[k] = src[e0 + i] | (dl << 17);
            bk[k] = b;
            atomicAdd(&cnt[b], 1);
        } else {
            bk[k] = -1;
        }
    }
    __syncthreads();

    if (t < 512) scn[t] = (t < NB) ? cnt[t] : 0;
    __syncthreads();
    for (int o = 1; o < 512; o <<= 1) {
        int x = 0;
        if (t < 512 && t >= o) x = scn[t - o];
        __syncthreads();
        if (t < 512) scn[t] += x;
        __syncthreads();
    }
    if (t < NB) {
        const int v    = cnt[t];
        const int excl = scn[t] - v;
        pos[t] = excl;
        cur[t] = excl;
        dlt[t] = atomicAdd(&gcur[t], v);     // relative base within bucket region
    }
    __syncthreads();

    #pragma unroll
    for (int k = 0; k < 8; ++k) {
        if (bk[k] >= 0) {
            const int p = atomicAdd(&cur[bk[k]], 1);
            recs[p] = pk[k];
        }
    }
    __syncthreads();

    const int w    = t >> 6;
    const int lane = t & 63;
    for (int b = w; b < NB; b += 16) {
        const int n = cnt[b];
        const int o = pos[b];
        const int g = b * CAP + dlt[b];      // absolute chunk base
        for (int i = lane; i < n; i += 64)
            packed[g + i] = recs[o + i];
    }
}

// ===========================================================================
// 2) Per-bucket CSR sort (in place, base = bucket*CAP)
// ===========================================================================
__global__ __launch_bounds__(512) void k_sortb(
    const int* __restrict__ gcur,
    int* packed,
    int* __restrict__ node_off, int* __restrict__ node_cnt)
{
    __shared__ int recs[CAP];        // 32 KB
    __shared__ int lcnt[256];
    __shared__ int sc[256];
    __shared__ int lcur[NPB];

    const int t      = threadIdx.x;
    const int bucket = blockIdx.x;
    const int base   = bucket * CAP;
    int total = gcur[bucket];
    if (total > CAP) total = CAP;

    if (t < 256) lcnt[t] = 0;
    __syncthreads();

    for (int i = t; i < total; i += 512) {
        const int r = packed[base + i];
        recs[i] = r;
        atomicAdd(&lcnt[r >> 17], 1);
    }
    __syncthreads();

    if (t < 256) sc[t] = lcnt[t];
    __syncthreads();
    for (int o = 1; o < 256; o <<= 1) {
        int x = 0;
        if (t < 256 && t >= o) x = sc[t - o];
        __syncthreads();
        if (t < 256) sc[t] += x;
        __syncthreads();
    }

    if (t < NPB) {
        const int excl = sc[t] - lcnt[t];
        lcur[t] = excl;
        const int n = bucket * NPB + t;
        if (n < N_NODES) {
            node_off[n] = base + excl;
            node_cnt[n] = lcnt[t];
        }
    }
    __syncthreads();

    for (int i = t; i < total; i += 512) {
        const int r   = recs[i];
        const int pos = atomicAdd(&lcur[r >> 17], 1);
        packed[base + pos] = r & 0x1FFFF;
    }
}

// ===========================================================================
// 3) Fused aggregate + MFMA update.  Block = 1024 thr = 16 waves = 16 nodes.
//    Phase 1: wave w aggregates node n0+w (f16 pk_add, zero-row sentinel),
//             writes mean-f16 to LDS (XOR-swizzled chunks).
//    Phase 2: barrier; wave 0 computes out[n0..n0+15][:] =
//             feat·WsT + mean·WnT with 16 mfma_f32_16x16x32_f16.
//    A: row=lane&15, k=(lane>>4)*8+j;  C/D: col=lane&15, row=(lane>>4)*4+r.
// ===========================================================================
__global__ __launch_bounds__(1024) void k_agg_update(
    const unsigned int* __restrict__ ff16,
    const int* __restrict__ node_off,
    const int* __restrict__ node_cnt,
    const int* __restrict__ packed,
    const _Float16* __restrict__ w16,     // [2][64][64]: Ws then Wn, K-major
    float* __restrict__ out)
{
    __shared__ uint4 meanLDS[16 * 8];     // [node][chunk^(node&7)]  2 KB

    const int t    = threadIdx.x;
    const int wv   = t >> 6;
    const int lane = t & 63;
    const int n0   = blockIdx.x * 16;
    const int n    = n0 + wv;

    // ---------------- phase 1: per-wave aggregation ----------------
    {
        const int start = node_off[n];
        const int deg   = node_cnt[n];
        const int sub   = lane >> 3;
        const int chunk = lane & 7;

        __half2 a0 = __floats2half2_rn(0.f, 0.f);
        __half2 a1 = a0, a2 = a0, a3 = a0;

        for (int b = 0; b < deg; b += 64) {
            const int rem = min(deg - b, 64);
            int p = ZROW;
            if (lane < rem) p = packed[start + b + lane];

            const int npair = (rem + 15) >> 4;
            for (int q = 0; q < npair; ++q) {
                const int e0 = q * 16 + sub;
                const int s0 = __shfl(p, e0)     & 0x1FFFF;
                const int s1 = __shfl(p, e0 + 8) & 0x1FFFF;
                const uint4 v0 = ((const uint4*)ff16)[(size_t)s0 * 8 + chunk];
                const uint4 v1 = ((const uint4*)ff16)[(size_t)s1 * 8 + chunk];
                a0 += bits2h(v0.x);
                a1 += bits2h(v0.y);
                a2 += bits2h(v0.z);
                a3 += bits2h(v0.w);
                a0 += bits2h(v1.x);
                a1 += bits2h(v1.y);
                a2 += bits2h(v1.z);
                a3 += bits2h(v1.w);
            }
        }

        #pragma unroll
        for (int mask = 8; mask <= 32; mask <<= 1) {
            a0 += h2shfl_xor(a0, mask);
            a1 += h2shfl_xor(a1, mask);
            a2 += h2shfl_xor(a2, mask);
            a3 += h2shfl_xor(a3, mask);
        }

        if (lane < 8) {
            const float inv = 1.0f / (float)((deg > 0) ? deg : 1);
            uint4 mb;
            mb.x = h2bits(__floats2half2_rn(__low2float(a0) * inv, __high2float(a0) * inv));
            mb.y = h2bits(__floats2half2_rn(__low2float(a1) * inv, __high2float(a1) * inv));
            mb.z = h2bits(__floats2half2_rn(__low2float(a2) * inv, __high2float(a2) * inv));
            mb.w = h2bits(__floats2half2_rn(__low2float(a3) * inv, __high2float(a3) * inv));
            meanLDS[wv * 8 + (lane ^ (wv & 7))] = mb;
        }
    }
    __syncthreads();

    // ---------------- phase 2: wave 0 MFMA update for the 16 nodes ----------
    if (wv != 0) return;

    const int r16 = lane & 15;
    const int g   = lane >> 4;

    half8 bws[4][2], bwn[4][2];
    #pragma unroll
    for (int nt = 0; nt < 4; ++nt) {
        const int c = nt * 16 + r16;
        #pragma unroll
        for (int kt = 0; kt < 2; ++kt) {
            const int k0 = kt * 32 + g * 8;
            bws[nt][kt] = *(const half8*)(w16 + c * 64 + k0);
            bwn[nt][kt] = *(const half8*)(w16 + 4096 + c * 64 + k0);
        }
    }

    f32x4 acc[4] = {{0.f,0.f,0.f,0.f}, {0.f,0.f,0.f,0.f},
                    {0.f,0.f,0.f,0.f}, {0.f,0.f,0.f,0.f}};

    #pragma unroll
    for (int kt = 0; kt < 2; ++kt) {
        const int k8 = kt * 4 + g;
        const uint4 af_u = ((const uint4*)ff16)[(size_t)(n0 + r16) * 8 + k8];
        const uint4 am_u = meanLDS[r16 * 8 + (k8 ^ (r16 & 7))];
        const half8 af = *(const half8*)&af_u;
        const half8 am = *(const half8*)&am_u;
        #pragma unroll
        for (int nt = 0; nt < 4; ++nt) {
            acc[nt] = __builtin_amdgcn_mfma_f32_16x16x32_f16(af, bws[nt][kt], acc[nt], 0, 0, 0);
            acc[nt] = __builtin_amdgcn_mfma_f32_16x16x32_f16(am, bwn[nt][kt], acc[nt], 0, 0, 0);
        }
    }

    #pragma unroll
    for (int nt = 0; nt < 4; ++nt) {
        #pragma unroll
        for (int r = 0; r < 4; ++r) {
            const int ro = n0 + g * 4 + r;
            out[(size_t)ro * 64 + nt * 16 + r16] = acc[nt][r];
        }
    }
}

// ===========================================================================
// tier-0 fallback (tiny ws): atomic scatter + readlane update
// ===========================================================================
__global__ __launch_bounds__(256) void sage_scatter(
    const float* __restrict__ feat,
    const int*   __restrict__ src,
    const int*   __restrict__ dst,
    float*       __restrict__ agg,
    float*       __restrict__ deg)
{
    const int gtid = blockIdx.x * blockDim.x + threadIdx.x;
    const int edge = gtid >> 6;
    const int lane = gtid & 63;
    if (edge >= N_EDGES) return;
    const int s = src[edge];
    const int d = dst[edge];
    atomicAdd(&agg[d * D + lane], feat[s * D + lane]);
    if (lane == 0) atomicAdd(&deg[d], 1.0f);
}

#define RL(v, l) __int_as_float(__builtin_amdgcn_readlane(__float_as_int(v), (l)))

__global__ __launch_bounds__(256) void k_update_div(
    const float* __restrict__ feat,
    const float* __restrict__ Ws,
    const float* __restrict__ Wn,
    const float* __restrict__ deg,
    float* out)
{
    const int wid   = (blockIdx.x * 256 + threadIdx.x) >> 6;
    const int lane  = threadIdx.x & 63;
    const int nwave = (gridDim.x * 256) >> 6;

    const float4* Ws4 = (const float4*)Ws;
    const float4* Wn4 = (const float4*)Wn;
    float4 ws[16], wn[16];
    #pragma unroll
    for (int j = 0; j < 16; ++j) {
        ws[j] = Ws4[lane * 16 + j];
        wn[j] = Wn4[lane * 16 + j];
    }

    for (int n = wid; n < N_NODES; n += nwave) {
        const float f = feat[n * D + lane];
        const float a = out[n * D + lane] / fmaxf(deg[n], 1.0f);
        float s0 = 0.f, s1 = 0.f, m0 = 0.f, m1 = 0.f;
        #pragma unroll
        for (int j = 0; j < 16; ++j) {
            const float4 w_s = ws[j];
            const float4 w_n = wn[j];
            s0 = fmaf(RL(f, 4 * j + 0), w_s.x, s0);
            s1 = fmaf(RL(f, 4 * j + 1), w_s.y, s1);
            s0 = fmaf(RL(f, 4 * j + 2), w_s.z, s0);
            s1 = fmaf(RL(f, 4 * j + 3), w_s.w, s1);
            m0 = fmaf(RL(a, 4 * j + 0), w_n.x, m0);
            m1 = fmaf(RL(a, 4 * j + 1), w_n.y, m1);
            m0 = fmaf(RL(a, 4 * j + 2), w_n.z, m0);
            m1 = fmaf(RL(a, 4 * j + 3), w_n.w, m1);
        }
        out[n * D + lane] = (s0 + s1) + (m0 + m1);
    }
}

extern "C" void kernel_launch(void* const* d_in, const int* in_sizes, int n_in,
                              void* d_out, int out_size, void* d_ws, size_t ws_size,
                              hipStream_t stream) {
    const float* feat = (const float*)d_in[0];
    const int*   src  = (const int*)d_in[1];
    const int*   dst  = (const int*)d_in[2];
    const float* Ws   = (const float*)d_in[3];
    const float* Wn   = (const float*)d_in[4];
    float* out = (float*)d_out;
    char*  ws  = (char*)d_ws;

    if (ws_size >= W3_NEED) {
        unsigned int* ff16 = (unsigned int*)(ws + W3_FF16);
        int* packed = (int*)(ws + W3_PACKED);
        int* gcur   = (int*)(ws + W3_GCUR);
        int* noff   = (int*)(ws + W3_NODEOFF);
        int* ncnt   = (int*)(ws + W3_NODECNT);
        unsigned int* w16u = (unsigned int*)(ws + W3_W16);

        hipMemsetAsync(gcur, 0, (size_t)NB * sizeof(int), stream);

        k_part_conv <<<PBLK + CONVB + 1, 1024, 0, stream>>>(
            feat, src, dst, Ws, Wn, ff16, w16u, gcur, packed);
        k_sortb     <<<NB, 512, 0, stream>>>(gcur, packed, noff, ncnt);
        k_agg_update<<<N_NODES / 16, 1024, 0, stream>>>(
            ff16, noff, ncnt, packed, (const _Float16*)w16u, out);
    } else {
        float* deg = (float*)ws;
        hipMemsetAsync(out, 0, (size_t)N_NODES * D * sizeof(float), stream);
        hipMemsetAsync(deg, 0, (size_t)N_NODES * sizeof(float), stream);
        sage_scatter<<<(N_EDGES * 64) / 256, 256, 0, stream>>>(feat, src, dst, out, deg);
        k_update_div<<<1024, 256, 0, stream>>>(feat, Ws, Wn, deg, out);
    }
}